// Round 2
// baseline (506.242 us; speedup 1.0000x reference)
//
#include <hip/hip_runtime.h>
#include <math.h>

#define DEVI __device__ __forceinline__

typedef __attribute__((ext_vector_type(4))) float f32x4;
typedef __attribute__((ext_vector_type(8))) short bf16x8;

// ---------- helpers ----------
DEVI short f2bf(float f) {                    // f32 -> bf16 (RNE)
    union { float f; unsigned u; } v; v.f = f;
    unsigned r = v.u + 0x7fffu + ((v.u >> 16) & 1u);
    return (short)(r >> 16);
}
DEVI float bf2f(short s) {
    union { unsigned u; float f; } v; v.u = ((unsigned)(unsigned short)s) << 16;
    return v.f;
}

DEVI f32x4 mfma16(bf16x8 a, bf16x8 b, f32x4 c) {
    return __builtin_amdgcn_mfma_f32_16x16x32_bf16(a, b, c, 0, 0, 0);
}

DEVI void gload16(const short* g, short* l) {  // async global->LDS, 16B/lane
    __builtin_amdgcn_global_load_lds((__attribute__((address_space(1))) void*)(g),
                                     (__attribute__((address_space(3))) void*)(l),
                                     16, 0, 0);
}

// ---------- elementwise f32 -> bf16 ----------
__global__ void k_cvt_bf16(const float* __restrict__ in, short* __restrict__ out, int n) {
    int i = (blockIdx.x * blockDim.x + threadIdx.x) * 4;
    if (i >= n) return;
    float4 v = *(const float4*)(in + i);
    short4 o;
    o.x = f2bf(v.x); o.y = f2bf(v.y); o.z = f2bf(v.z); o.w = f2bf(v.w);
    *(short4*)(out + i) = o;
}

// ---------- transpose + convert: in f32 [R][C] -> out bf16 [Cpad][Rpad], zero pad ----------
__global__ void k_transpose_cvt(const float* __restrict__ in, short* __restrict__ out,
                                int R, int C, int Rpad, int Cpad) {
    __shared__ float tile[32][33];
    int c0 = blockIdx.x * 32;   // C-dim (out rows)
    int r0 = blockIdx.y * 32;   // R-dim (out cols)
    int tx = threadIdx.x & 31, ty = threadIdx.x >> 5;   // ty in [0,8)
#pragma unroll
    for (int i = 0; i < 4; i++) {
        int r = r0 + ty + 8 * i, c = c0 + tx;
        tile[ty + 8 * i][tx] = (r < R && c < C) ? in[(size_t)r * C + c] : 0.0f;
    }
    __syncthreads();
#pragma unroll
    for (int i = 0; i < 4; i++) {
        int oc = c0 + ty + 8 * i;   // out row
        int orr = r0 + tx;          // out col
        if (oc < Cpad && orr < Rpad)
            out[(size_t)oc * Rpad + orr] = f2bf(tile[tx][ty + 8 * i]);
    }
}

// ---------- RoPE freq tables (f64 for reference fidelity) ----------
__global__ void k_freqs(float* __restrict__ cost, float* __restrict__ sint) {
    int i = blockIdx.x * blockDim.x + threadIdx.x;   // [0, 2048*32)
    int s = i >> 5, j = i & 31;
    double inv = pow(10000.0, -(double)j / 32.0);
    double f = (double)s * inv;
    cost[i] = (float)cos(f);
    sint[i] = (float)sin(f);
}

// ---------- GEMM: C = A bf16[M][K] * BT bf16[N][K], 128x128x32; OUT_BF16 selects C dtype ----------
template <int OUT_BF16>
__launch_bounds__(256)
__global__ void k_gemm128(const short* __restrict__ A, const short* __restrict__ BT,
                          void* __restrict__ Cv, int M, int N, int K) {
    __shared__ __align__(16) short As[128 * 32];
    __shared__ __align__(16) short Bs[128 * 32];
    const int t = threadIdx.x;
    const int w = t >> 6;
    const int lane = t & 63;
    const int lr = lane & 15, lg = lane >> 4;
    const int m0 = blockIdx.x * 128, n0 = blockIdx.y * 128;
    const int wr = (w >> 1) * 64, wc = (w & 1) * 64;

    f32x4 acc[4][4];
#pragma unroll
    for (int m = 0; m < 4; m++)
#pragma unroll
        for (int n = 0; n < 4; n++)
            acc[m][n] = (f32x4){0.f, 0.f, 0.f, 0.f};

    const int nk = K >> 5;
    for (int kt = 0; kt < nk; kt++) {
        const int k0 = kt << 5;
#pragma unroll
        for (int j = 0; j < 2; j++) {
            int c = t + (j << 8);
            int row = c >> 2, col = (c & 3) << 3;
            gload16(A + (size_t)(m0 + row) * K + k0 + col,
                    As + (size_t)(w * 64 + (j << 8)) * 8);
            gload16(BT + (size_t)(n0 + row) * K + k0 + col,
                    Bs + (size_t)(w * 64 + (j << 8)) * 8);
        }
        __syncthreads();
        bf16x8 af[4], bfr[4];
#pragma unroll
        for (int m = 0; m < 4; m++)
            af[m] = *(const bf16x8*)&As[(wr + m * 16 + lr) * 32 + lg * 8];
#pragma unroll
        for (int n = 0; n < 4; n++)
            bfr[n] = *(const bf16x8*)&Bs[(wc + n * 16 + lr) * 32 + lg * 8];
#pragma unroll
        for (int m = 0; m < 4; m++)
#pragma unroll
            for (int n = 0; n < 4; n++)
                acc[m][n] = mfma16(af[m], bfr[n], acc[m][n]);
        __syncthreads();
    }
#pragma unroll
    for (int m = 0; m < 4; m++)
#pragma unroll
        for (int n = 0; n < 4; n++) {
            int row = m0 + wr + m * 16 + lg * 4;
            int col = n0 + wc + n * 16 + lr;
#pragma unroll
            for (int i = 0; i < 4; i++) {
                if (OUT_BF16)
                    ((short*)Cv)[(size_t)(row + i) * N + col] = f2bf(acc[m][n][i]);
                else
                    ((float*)Cv)[(size_t)(row + i) * N + col] = acc[m][n][i];
            }
        }
}

// ---------- dual GEMM + SwiGLU: w = (A*BTu)*s_u * silu((A*BTg)*s_v*32), bf16 out ----------
__launch_bounds__(256)
__global__ void k_gemm_dual(const short* __restrict__ A, const short* __restrict__ BTu,
                            const short* __restrict__ BTg, const float* __restrict__ s_u,
                            const float* __restrict__ s_v, short* __restrict__ Wout,
                            int M, int N, int K) {
    __shared__ __align__(16) short As[128 * 32];
    __shared__ __align__(16) short Bus[64 * 32];
    __shared__ __align__(16) short Bgs[64 * 32];
    const int t = threadIdx.x;
    const int w = t >> 6;
    const int lane = t & 63;
    const int lr = lane & 15, lg = lane >> 4;
    const int m0 = blockIdx.x * 128, n0 = blockIdx.y * 64;
    const int wr = (w >> 1) * 64, wc = (w & 1) * 32;

    f32x4 aU[4][2], aG[4][2];
#pragma unroll
    for (int m = 0; m < 4; m++)
#pragma unroll
        for (int n = 0; n < 2; n++) {
            aU[m][n] = (f32x4){0.f, 0.f, 0.f, 0.f};
            aG[m][n] = (f32x4){0.f, 0.f, 0.f, 0.f};
        }

    const int nk = K >> 5;
    for (int kt = 0; kt < nk; kt++) {
        const int k0 = kt << 5;
#pragma unroll
        for (int j = 0; j < 2; j++) {
            int c = t + (j << 8);
            gload16(A + (size_t)(m0 + (c >> 2)) * K + k0 + ((c & 3) << 3),
                    As + (size_t)(w * 64 + (j << 8)) * 8);
        }
        {
            int row = t >> 2, col = (t & 3) << 3;
            gload16(BTu + (size_t)(n0 + row) * K + k0 + col, Bus + (size_t)(w * 64) * 8);
            gload16(BTg + (size_t)(n0 + row) * K + k0 + col, Bgs + (size_t)(w * 64) * 8);
        }
        __syncthreads();
        bf16x8 af[4], bu[2], bg[2];
#pragma unroll
        for (int m = 0; m < 4; m++)
            af[m] = *(const bf16x8*)&As[(wr + m * 16 + lr) * 32 + lg * 8];
#pragma unroll
        for (int n = 0; n < 2; n++) {
            bu[n] = *(const bf16x8*)&Bus[(wc + n * 16 + lr) * 32 + lg * 8];
            bg[n] = *(const bf16x8*)&Bgs[(wc + n * 16 + lr) * 32 + lg * 8];
        }
#pragma unroll
        for (int m = 0; m < 4; m++)
#pragma unroll
            for (int n = 0; n < 2; n++) {
                aU[m][n] = mfma16(af[m], bu[n], aU[m][n]);
                aG[m][n] = mfma16(af[m], bg[n], aG[m][n]);
            }
        __syncthreads();
    }
#pragma unroll
    for (int m = 0; m < 4; m++)
#pragma unroll
        for (int n = 0; n < 2; n++) {
            int col = n0 + wc + n * 16 + lr;
            int jc = col < 2730 ? col : 0;
            float su = s_u[jc];
            float sg = s_v[jc] * 32.0f;
#pragma unroll
            for (int i = 0; i < 4; i++) {
                int row = m0 + wr + m * 16 + lg * 4 + i;
                float uu = aU[m][n][i] * su;
                float vv = aG[m][n][i] * sg;
                float sig = 1.0f / (1.0f + expf(-vv));
                Wout[(size_t)row * N + col] = f2bf(uu * vv * sig);
            }
        }
}

// ---------- RoPE + cosine_norm for q,k. qkvb bf16 [4096][3072] -> qn,kn bf16 [B][H][S][64] ----------
__global__ void k_rope(const short* __restrict__ qkvb, const float* __restrict__ cost,
                       const float* __restrict__ sint, const float* __restrict__ sqk,
                       short* __restrict__ qn, short* __restrict__ kn) {
    int wid = blockIdx.x * 4 + (threadIdx.x >> 6);   // [0, 65536)
    int lane = threadIdx.x & 63;
    int h = wid & 15;
    int s = (wid >> 4) & 2047;
    int b = wid >> 15;
    int row = b * 2048 + s;
    int j = lane & 31;
    float cs = cost[s * 32 + j];
    float sn = sint[s * 32 + j];
    float eff = sqk[h * 64 + lane] * 32.0f;          // s_qk * sqrt(DIM)
    size_t inbase = (size_t)row * 3072 + h * 64 + lane;
    size_t outbase = ((size_t)(b * 16 + h) * 2048 + s) * 64 + lane;
    {   // q  (extra *8 = sqrt(HD) logit scale folded in)
        float v = bf2f(qkvb[inbase]);
        float vp = __shfl_xor(v, 32, 64);
        float vr = (lane < 32) ? v * cs - vp * sn : v * cs + vp * sn;
        float ss = vr * vr;
#pragma unroll
        for (int o = 1; o < 64; o <<= 1) ss += __shfl_xor(ss, o, 64);
        float sc = eff * 8.0f / fmaxf(sqrtf(ss), 1e-6f);
        qn[outbase] = f2bf(vr * sc);
    }
    {   // k
        float v = bf2f(qkvb[inbase + 1024]);
        float vp = __shfl_xor(v, 32, 64);
        float vr = (lane < 32) ? v * cs - vp * sn : v * cs + vp * sn;
        float ss = vr * vr;
#pragma unroll
        for (int o = 1; o < 64; o <<= 1) ss += __shfl_xor(ss, o, 64);
        float sc = eff / fmaxf(sqrtf(ss), 1e-6f);
        kn[outbase] = f2bf(vr * sc);
    }
}

// ---------- V transpose: qkvb v-part bf16 -> vt bf16 [B][H][64][2048] ----------
__global__ void k_vtrans(const short* __restrict__ qkvb, short* __restrict__ vt) {
    __shared__ short tile[64][72];
    int blk = blockIdx.x;
    int st = blk & 31, h = (blk >> 5) & 15, b = blk >> 9;
    int s0 = st * 64;
    int t = threadIdx.x;
    int sl = t >> 2, c0 = (t & 3) * 16;
    const short* src = qkvb + (size_t)(b * 2048 + s0 + sl) * 3072 + 2048 + h * 64 + c0;
    bf16x8 a0 = *(const bf16x8*)src;
    bf16x8 a1 = *(const bf16x8*)(src + 8);
#pragma unroll
    for (int jj = 0; jj < 8; jj++) { tile[sl][c0 + jj] = a0[jj]; tile[sl][c0 + 8 + jj] = a1[jj]; }
    __syncthreads();
    int hd = t >> 2, sc = (t & 3) * 16;
    bf16x8 p0, p1;
#pragma unroll
    for (int jj = 0; jj < 8; jj++) { p0[jj] = tile[sc + jj][hd]; p1[jj] = tile[sc + 8 + jj][hd]; }
    size_t obase = ((size_t)((b * 16 + h) * 64 + hd)) * 2048 + s0 + sc;
    *(bf16x8*)&vt[obase] = p0;
    *(bf16x8*)&vt[obase + 8] = p1;
}

// ---------- flash attention (causal). qn,kn [B][H][S][64], vt [B][H][64][S] -> ao bf16 [4096][1024] ----------
__launch_bounds__(256)
__global__ void k_attn(const short* __restrict__ qn, const short* __restrict__ kn,
                       const short* __restrict__ vt, short* __restrict__ ao) {
    __shared__ __align__(16) short plds[4][512];
    const int t = threadIdx.x;
    const int w = t >> 6, lane = t & 63;
    const int qb = blockIdx.x, h = blockIdx.y, b = blockIdx.z;
    const int bh = b * 16 + h;
    const int q0 = qb * 64 + w * 16;
    const int lr = lane & 15, lg = lane >> 4;
    const short* Qb = qn + (size_t)bh * 2048 * 64;
    const short* Kb = kn + (size_t)bh * 2048 * 64;
    const short* Vb = vt + (size_t)bh * 64 * 2048;
    char* pw = (char*)&plds[w][0];

    bf16x8 qf0 = *(const bf16x8*)&Qb[(size_t)(q0 + lr) * 64 + lg * 8];
    bf16x8 qf1 = *(const bf16x8*)&Qb[(size_t)(q0 + lr) * 64 + 32 + lg * 8];

    f32x4 oacc[4];
#pragma unroll
    for (int ct = 0; ct < 4; ct++) oacc[ct] = (f32x4){0.f, 0.f, 0.f, 0.f};
    float mrow[4], lsum[4];
#pragma unroll
    for (int i = 0; i < 4; i++) { mrow[i] = -3.0e38f; lsum[i] = 0.0f; }

    const int ktend = (q0 + 15) / 32 + 1;
    for (int kt = 0; kt < ktend; kt++) {
        const int kbase = kt << 5;
        f32x4 sv[2];
#pragma unroll
        for (int tt = 0; tt < 2; tt++) {
            const short* kr = Kb + (size_t)(kbase + tt * 16 + lr) * 64;
            bf16x8 kf0 = *(const bf16x8*)(kr + lg * 8);
            bf16x8 kf1 = *(const bf16x8*)(kr + 32 + lg * 8);
            f32x4 s = (f32x4){0.f, 0.f, 0.f, 0.f};
            s = mfma16(qf0, kf0, s);
            s = mfma16(qf1, kf1, s);
            sv[tt] = s;
        }
        float mx[4];
#pragma unroll
        for (int i = 0; i < 4; i++) {
            int qg = q0 + lg * 4 + i;
#pragma unroll
            for (int tt = 0; tt < 2; tt++) {
                int kg = kbase + tt * 16 + lr;
                if (kg > qg) sv[tt][i] = -3.0e38f;
            }
            mx[i] = fmaxf(sv[0][i], sv[1][i]);
        }
#pragma unroll
        for (int o = 1; o < 16; o <<= 1)
#pragma unroll
            for (int i = 0; i < 4; i++)
                mx[i] = fmaxf(mx[i], __shfl_xor(mx[i], o, 64));
        float al[4];
#pragma unroll
        for (int i = 0; i < 4; i++) {
            float mn = fmaxf(mrow[i], mx[i]);
            al[i] = exp2f((mrow[i] - mn) * 1.44269504f);
            mrow[i] = mn;
        }
        float pv[2][4];
        float ps[4] = {0.f, 0.f, 0.f, 0.f};
#pragma unroll
        for (int tt = 0; tt < 2; tt++)
#pragma unroll
            for (int i = 0; i < 4; i++) {
                float p = exp2f((sv[tt][i] - mrow[i]) * 1.44269504f);
                pv[tt][i] = p;
                ps[i] += p;
            }
#pragma unroll
        for (int o = 1; o < 16; o <<= 1)
#pragma unroll
            for (int i = 0; i < 4; i++)
                ps[i] += __shfl_xor(ps[i], o, 64);
#pragma unroll
        for (int i = 0; i < 4; i++)
            lsum[i] = lsum[i] * al[i] + ps[i];
#pragma unroll
        for (int ct = 0; ct < 4; ct++)
#pragma unroll
            for (int i = 0; i < 4; i++)
                oacc[ct][i] *= al[i];
        // P: C-layout -> A-layout via per-wave XOR-swizzled LDS round-trip
#pragma unroll
        for (int tt = 0; tt < 2; tt++)
#pragma unroll
            for (int i = 0; i < 4; i++) {
                int row = lg * 4 + i;
                int col = tt * 16 + lr;
                unsigned off = (unsigned)((row * 32 + col) * 2) ^ (unsigned)((row & 7) << 4);
                *(short*)(pw + off) = f2bf(pv[tt][i]);
            }
        bf16x8 pf;
        {
            unsigned off = (unsigned)(lr * 64 + lg * 16) ^ (unsigned)((lr & 7) << 4);
            pf = *(const bf16x8*)(pw + off);
        }
#pragma unroll
        for (int ct = 0; ct < 4; ct++) {
            bf16x8 vf = *(const bf16x8*)&Vb[(size_t)(ct * 16 + lr) * 2048 + kbase + lg * 8];
            oacc[ct] = mfma16(pf, vf, oacc[ct]);
        }
    }
    float rl[4];
#pragma unroll
    for (int i = 0; i < 4; i++) rl[i] = 1.0f / lsum[i];
    short* aob = ao + ((size_t)(b * 2048 + q0) * 1024) + h * 64;
#pragma unroll
    for (int ct = 0; ct < 4; ct++)
#pragma unroll
        for (int i = 0; i < 4; i++) {
            int q = lg * 4 + i;
            aob[(size_t)q * 1024 + ct * 16 + lr] = f2bf(oacc[ct][i] * rl[i]);
        }
}

// ---------- residual + double cosine_norm (base/outf may alias: no restrict on them) ----------
__global__ void k_resnorm(const float* base, const float* __restrict__ pre,
                          const float* __restrict__ alpha, float* outf,
                          short* __restrict__ outb) {
    __shared__ float red1[4], red2[4];
    int row = blockIdx.x;
    int t = threadIdx.x;
    int w = t >> 6;
    const float4 p = *(const float4*)(pre + (size_t)row * 1024 + t * 4);
    float ss = p.x * p.x + p.y * p.y + p.z * p.z + p.w * p.w;
#pragma unroll
    for (int o = 1; o < 64; o <<= 1) ss += __shfl_xor(ss, o, 64);
    if ((t & 63) == 0) red1[w] = ss;
    __syncthreads();
    float inv1 = 1.0f / fmaxf(sqrtf(red1[0] + red1[1] + red1[2] + red1[3]), 1e-6f);
    const float4 bx = *(const float4*)(base + (size_t)row * 1024 + t * 4);
    const float4 av = *(const float4*)(alpha + t * 4);
    float4 tm;
    tm.x = bx.x + av.x * (p.x * inv1 - bx.x);
    tm.y = bx.y + av.y * (p.y * inv1 - bx.y);
    tm.z = bx.z + av.z * (p.z * inv1 - bx.z);
    tm.w = bx.w + av.w * (p.w * inv1 - bx.w);
    float ss2 = tm.x * tm.x + tm.y * tm.y + tm.z * tm.z + tm.w * tm.w;
#pragma unroll
    for (int o = 1; o < 64; o <<= 1) ss2 += __shfl_xor(ss2, o, 64);
    if ((t & 63) == 0) red2[w] = ss2;
    __syncthreads();
    float inv2 = 1.0f / fmaxf(sqrtf(red2[0] + red2[1] + red2[2] + red2[3]), 1e-6f);
    float4 hv;
    hv.x = tm.x * inv2; hv.y = tm.y * inv2; hv.z = tm.z * inv2; hv.w = tm.w * inv2;
    if (outf) *(float4*)(outf + (size_t)row * 1024 + t * 4) = hv;
    if (outb) {
        short4 o4;
        o4.x = f2bf(hv.x); o4.y = f2bf(hv.y); o4.z = f2bf(hv.z); o4.w = f2bf(hv.w);
        *(short4*)(outb + (size_t)row * 1024 + t * 4) = o4;
    }
}

// ---------- launch ----------
// Workspace layout (bytes), lifetime-overlaid; peak use = 76,152,832 B (72.6 MiB).
//   [0,25821184)        weights (bf16, transposed) + rope tables   (whole launch)
//   XBF   25821184      x as bf16            #1 -> #4
//   QKVB  34209792      qkv bf16 [4096][3072] #4 -> #6
//   QN    59375616      q normed             #5 -> #7
//   KN    67764224      k normed             #5 -> #7
//   VT    25821184      v^T (reuse XBF)      #6 -> #7
//   AO    34209792      attn out (reuse QKVB) #7 -> #8
//   HA    42598400      attn@Wo f32          #8 -> #9
//   H1F   = d_out       post-attn hidden f32 #9 -> #12 (in-place final norm)
//   H1BF  25821184      h1 bf16 (reuse VT)   #9 -> #10
//   WMLP  34209792      swiglu out (reuse AO/HA) #10 -> #11
//   HM    59375616      mlp@Wdown f32 (reuse QN/KN) #11 -> #12
extern "C" void kernel_launch(void* const* d_in, const int* in_sizes, int n_in,
                              void* d_out, int out_size, void* d_ws, size_t ws_size,
                              hipStream_t stream) {
    (void)in_sizes; (void)n_in; (void)out_size; (void)ws_size;
    const float* x   = (const float*)d_in[0];
    const float* Wq  = (const float*)d_in[1];
    const float* Wk  = (const float*)d_in[2];
    const float* Wv  = (const float*)d_in[3];
    const float* Wo  = (const float*)d_in[4];
    const float* sqk = (const float*)d_in[5];
    const float* aA  = (const float*)d_in[6];
    const float* Wup = (const float*)d_in[7];
    const float* Wg  = (const float*)d_in[8];
    const float* Wd  = (const float*)d_in[9];
    const float* su  = (const float*)d_in[10];
    const float* sv  = (const float*)d_in[11];
    const float* aM  = (const float*)d_in[12];

    char* ws = (char*)d_ws;
    short* wqkvT  = (short*)(ws + 0);          // [3072][1024]
    short* woT    = (short*)(ws + 6291456);    // [1024][1024]
    short* wupT   = (short*)(ws + 8388608);    // [2752][1024]
    short* wgateT = (short*)(ws + 14024704);   // [2752][1024]
    short* wdownT = (short*)(ws + 19660800);   // [1024][2752]
    float* cost   = (float*)(ws + 25296896);
    float* sint   = (float*)(ws + 25559040);
    short* xbf    = (short*)(ws + 25821184);
    short* qkvb   = (short*)(ws + 34209792);   // [4096][3072] bf16
    short* qn     = (short*)(ws + 59375616);
    short* kn     = (short*)(ws + 67764224);
    short* vt     = (short*)(ws + 25821184);   // reuse xbf
    short* ao     = (short*)(ws + 34209792);   // reuse qkvb
    float* hA     = (float*)(ws + 42598400);
    float* h1f    = (float*)d_out;             // d_out doubles as h1 storage
    short* h1bf   = (short*)(ws + 25821184);   // reuse vt
    short* wmlp   = (short*)(ws + 34209792);   // reuse ao/hA: [4096][2752]
    float* hM     = (float*)(ws + 59375616);   // reuse qn/kn

    k_cvt_bf16<<<4096, 256, 0, stream>>>(x, xbf, 4194304);
    k_transpose_cvt<<<dim3(32, 32), 256, 0, stream>>>(Wq, wqkvT,           1024, 1024, 1024, 1024);
    k_transpose_cvt<<<dim3(32, 32), 256, 0, stream>>>(Wk, wqkvT + 1048576, 1024, 1024, 1024, 1024);
    k_transpose_cvt<<<dim3(32, 32), 256, 0, stream>>>(Wv, wqkvT + 2097152, 1024, 1024, 1024, 1024);
    k_transpose_cvt<<<dim3(32, 32), 256, 0, stream>>>(Wo, woT,             1024, 1024, 1024, 1024);
    k_transpose_cvt<<<dim3(86, 32), 256, 0, stream>>>(Wup, wupT,   1024, 2730, 1024, 2752);
    k_transpose_cvt<<<dim3(86, 32), 256, 0, stream>>>(Wg,  wgateT, 1024, 2730, 1024, 2752);
    k_transpose_cvt<<<dim3(32, 86), 256, 0, stream>>>(Wd,  wdownT, 2730, 1024, 2752, 1024);
    k_freqs<<<256, 256, 0, stream>>>(cost, sint);

    k_gemm128<1><<<dim3(32, 24), 256, 0, stream>>>(xbf, wqkvT, qkvb, 4096, 3072, 1024);
    k_rope<<<16384, 256, 0, stream>>>(qkvb, cost, sint, sqk, qn, kn);
    k_vtrans<<<1024, 256, 0, stream>>>(qkvb, vt);
    k_attn<<<dim3(32, 16, 2), 256, 0, stream>>>(qn, kn, vt, ao);
    k_gemm128<0><<<dim3(32, 8), 256, 0, stream>>>(ao, woT, hA, 4096, 1024, 1024);
    k_resnorm<<<4096, 256, 0, stream>>>(x, hA, aA, h1f, h1bf);
    k_gemm_dual<<<dim3(32, 43), 256, 0, stream>>>(h1bf, wupT, wgateT, su, sv, wmlp, 4096, 2752, 1024);
    k_gemm128<0><<<dim3(32, 8), 256, 0, stream>>>(wmlp, wdownT, hM, 4096, 1024, 2752);
    k_resnorm<<<4096, 256, 0, stream>>>(h1f, hM, aM, (float*)d_out, (short*)nullptr);
}

// Round 3
// 411.559 us; speedup vs baseline: 1.2301x; 1.2301x over previous
//
#include <hip/hip_runtime.h>
#include <math.h>

#define DEVI __device__ __forceinline__

typedef __attribute__((ext_vector_type(4))) float f32x4;
typedef __attribute__((ext_vector_type(8))) short bf16x8;

// ---------- helpers ----------
DEVI short f2bf(float f) {                    // f32 -> bf16 (RNE)
    union { float f; unsigned u; } v; v.f = f;
    unsigned r = v.u + 0x7fffu + ((v.u >> 16) & 1u);
    return (short)(r >> 16);
}
DEVI float bf2f(short s) {
    union { unsigned u; float f; } v; v.u = ((unsigned)(unsigned short)s) << 16;
    return v.f;
}

DEVI f32x4 mfma16(bf16x8 a, bf16x8 b, f32x4 c) {
    return __builtin_amdgcn_mfma_f32_16x16x32_bf16(a, b, c, 0, 0, 0);
}

DEVI void gload16(const short* g, short* l) {  // async global->LDS, 16B/lane
    __builtin_amdgcn_global_load_lds((__attribute__((address_space(1))) void*)(g),
                                     (__attribute__((address_space(3))) void*)(l),
                                     16, 0, 0);
}

// ---------- elementwise f32 -> bf16 ----------
__global__ void k_cvt_bf16(const float* __restrict__ in, short* __restrict__ out, int n) {
    int i = (blockIdx.x * blockDim.x + threadIdx.x) * 4;
    if (i >= n) return;
    float4 v = *(const float4*)(in + i);
    short4 o;
    o.x = f2bf(v.x); o.y = f2bf(v.y); o.z = f2bf(v.z); o.w = f2bf(v.w);
    *(short4*)(out + i) = o;
}

// ---------- transpose + convert: in f32 [R][C] -> out bf16 [Cpad][Rpad], zero pad ----------
__global__ void k_transpose_cvt(const float* __restrict__ in, short* __restrict__ out,
                                int R, int C, int Rpad, int Cpad) {
    __shared__ float tile[32][33];
    int c0 = blockIdx.x * 32;   // C-dim (out rows)
    int r0 = blockIdx.y * 32;   // R-dim (out cols)
    int tx = threadIdx.x & 31, ty = threadIdx.x >> 5;   // ty in [0,8)
#pragma unroll
    for (int i = 0; i < 4; i++) {
        int r = r0 + ty + 8 * i, c = c0 + tx;
        tile[ty + 8 * i][tx] = (r < R && c < C) ? in[(size_t)r * C + c] : 0.0f;
    }
    __syncthreads();
#pragma unroll
    for (int i = 0; i < 4; i++) {
        int oc = c0 + ty + 8 * i;   // out row
        int orr = r0 + tx;          // out col
        if (oc < Cpad && orr < Rpad)
            out[(size_t)oc * Rpad + orr] = f2bf(tile[tx][ty + 8 * i]);
    }
}

// ---------- RoPE freq tables (f64 for reference fidelity) ----------
__global__ void k_freqs(float* __restrict__ cost, float* __restrict__ sint) {
    int i = blockIdx.x * blockDim.x + threadIdx.x;   // [0, 2048*32)
    int s = i >> 5, j = i & 31;
    double inv = pow(10000.0, -(double)j / 32.0);
    double f = (double)s * inv;
    cost[i] = (float)cos(f);
    sint[i] = (float)sin(f);
}

// ---------- GEMM: C = A bf16[M][K] * BT bf16[N][K], 128x128x32; OUT_BF16 selects C dtype ----------
template <int OUT_BF16>
__launch_bounds__(256)
__global__ void k_gemm128(const short* __restrict__ A, const short* __restrict__ BT,
                          void* __restrict__ Cv, int M, int N, int K) {
    __shared__ __align__(16) short As[128 * 32];
    __shared__ __align__(16) short Bs[128 * 32];
    const int t = threadIdx.x;
    const int w = t >> 6;
    const int lane = t & 63;
    const int lr = lane & 15, lg = lane >> 4;
    const int m0 = blockIdx.x * 128, n0 = blockIdx.y * 128;
    const int wr = (w >> 1) * 64, wc = (w & 1) * 64;

    f32x4 acc[4][4];
#pragma unroll
    for (int m = 0; m < 4; m++)
#pragma unroll
        for (int n = 0; n < 4; n++)
            acc[m][n] = (f32x4){0.f, 0.f, 0.f, 0.f};

    const int nk = K >> 5;
    for (int kt = 0; kt < nk; kt++) {
        const int k0 = kt << 5;
#pragma unroll
        for (int j = 0; j < 2; j++) {
            int c = t + (j << 8);
            int row = c >> 2, col = (c & 3) << 3;
            gload16(A + (size_t)(m0 + row) * K + k0 + col,
                    As + (size_t)(w * 64 + (j << 8)) * 8);
            gload16(BT + (size_t)(n0 + row) * K + k0 + col,
                    Bs + (size_t)(w * 64 + (j << 8)) * 8);
        }
        __syncthreads();
        bf16x8 af[4], bfr[4];
#pragma unroll
        for (int m = 0; m < 4; m++)
            af[m] = *(const bf16x8*)&As[(wr + m * 16 + lr) * 32 + lg * 8];
#pragma unroll
        for (int n = 0; n < 4; n++)
            bfr[n] = *(const bf16x8*)&Bs[(wc + n * 16 + lr) * 32 + lg * 8];
#pragma unroll
        for (int m = 0; m < 4; m++)
#pragma unroll
            for (int n = 0; n < 4; n++)
                acc[m][n] = mfma16(af[m], bfr[n], acc[m][n]);
        __syncthreads();
    }
#pragma unroll
    for (int m = 0; m < 4; m++)
#pragma unroll
        for (int n = 0; n < 4; n++) {
            int row = m0 + wr + m * 16 + lg * 4;
            int col = n0 + wc + n * 16 + lr;
#pragma unroll
            for (int i = 0; i < 4; i++) {
                if (OUT_BF16)
                    ((short*)Cv)[(size_t)(row + i) * N + col] = f2bf(acc[m][n][i]);
                else
                    ((float*)Cv)[(size_t)(row + i) * N + col] = acc[m][n][i];
            }
        }
}

// ---------- dual GEMM + SwiGLU: w = (A*BTu)*s_u * silu((A*BTg)*s_v*32), bf16 out ----------
__launch_bounds__(256)
__global__ void k_gemm_dual(const short* __restrict__ A, const short* __restrict__ BTu,
                            const short* __restrict__ BTg, const float* __restrict__ s_u,
                            const float* __restrict__ s_v, short* __restrict__ Wout,
                            int M, int N, int K) {
    __shared__ __align__(16) short As[128 * 32];
    __shared__ __align__(16) short Bus[64 * 32];
    __shared__ __align__(16) short Bgs[64 * 32];
    const int t = threadIdx.x;
    const int w = t >> 6;
    const int lane = t & 63;
    const int lr = lane & 15, lg = lane >> 4;
    const int m0 = blockIdx.x * 128, n0 = blockIdx.y * 64;
    const int wr = (w >> 1) * 64, wc = (w & 1) * 32;

    f32x4 aU[4][2], aG[4][2];
#pragma unroll
    for (int m = 0; m < 4; m++)
#pragma unroll
        for (int n = 0; n < 2; n++) {
            aU[m][n] = (f32x4){0.f, 0.f, 0.f, 0.f};
            aG[m][n] = (f32x4){0.f, 0.f, 0.f, 0.f};
        }

    const int nk = K >> 5;
    for (int kt = 0; kt < nk; kt++) {
        const int k0 = kt << 5;
#pragma unroll
        for (int j = 0; j < 2; j++) {
            int c = t + (j << 8);
            gload16(A + (size_t)(m0 + (c >> 2)) * K + k0 + ((c & 3) << 3),
                    As + (size_t)(w * 64 + (j << 8)) * 8);
        }
        {
            int row = t >> 2, col = (t & 3) << 3;
            gload16(BTu + (size_t)(n0 + row) * K + k0 + col, Bus + (size_t)(w * 64) * 8);
            gload16(BTg + (size_t)(n0 + row) * K + k0 + col, Bgs + (size_t)(w * 64) * 8);
        }
        __syncthreads();
        bf16x8 af[4], bu[2], bg[2];
#pragma unroll
        for (int m = 0; m < 4; m++)
            af[m] = *(const bf16x8*)&As[(wr + m * 16 + lr) * 32 + lg * 8];
#pragma unroll
        for (int n = 0; n < 2; n++) {
            bu[n] = *(const bf16x8*)&Bus[(wc + n * 16 + lr) * 32 + lg * 8];
            bg[n] = *(const bf16x8*)&Bgs[(wc + n * 16 + lr) * 32 + lg * 8];
        }
#pragma unroll
        for (int m = 0; m < 4; m++)
#pragma unroll
            for (int n = 0; n < 2; n++) {
                aU[m][n] = mfma16(af[m], bu[n], aU[m][n]);
                aG[m][n] = mfma16(af[m], bg[n], aG[m][n]);
            }
        __syncthreads();
    }
#pragma unroll
    for (int m = 0; m < 4; m++)
#pragma unroll
        for (int n = 0; n < 2; n++) {
            int col = n0 + wc + n * 16 + lr;
            int jc = col < 2730 ? col : 0;
            float su = s_u[jc];
            float sg = s_v[jc] * 32.0f;
#pragma unroll
            for (int i = 0; i < 4; i++) {
                int row = m0 + wr + m * 16 + lg * 4 + i;
                float uu = aU[m][n][i] * su;
                float vv = aG[m][n][i] * sg;
                float sig = 1.0f / (1.0f + expf(-vv));
                Wout[(size_t)row * N + col] = f2bf(uu * vv * sig);
            }
        }
}

// ---------- RoPE + cosine_norm for q,k. qkvb bf16 [4096][3072] -> qn,kn bf16 [B][H][S][64] ----------
__global__ void k_rope(const short* __restrict__ qkvb, const float* __restrict__ cost,
                       const float* __restrict__ sint, const float* __restrict__ sqk,
                       short* __restrict__ qn, short* __restrict__ kn) {
    int wid = blockIdx.x * 4 + (threadIdx.x >> 6);   // [0, 65536)
    int lane = threadIdx.x & 63;
    int h = wid & 15;
    int s = (wid >> 4) & 2047;
    int b = wid >> 15;
    int row = b * 2048 + s;
    int j = lane & 31;
    float cs = cost[s * 32 + j];
    float sn = sint[s * 32 + j];
    float eff = sqk[h * 64 + lane] * 32.0f;          // s_qk * sqrt(DIM)
    size_t inbase = (size_t)row * 3072 + h * 64 + lane;
    size_t outbase = ((size_t)(b * 16 + h) * 2048 + s) * 64 + lane;
    {   // q  (extra *8 = sqrt(HD) logit scale folded in)
        float v = bf2f(qkvb[inbase]);
        float vp = __shfl_xor(v, 32, 64);
        float vr = (lane < 32) ? v * cs - vp * sn : v * cs + vp * sn;
        float ss = vr * vr;
#pragma unroll
        for (int o = 1; o < 64; o <<= 1) ss += __shfl_xor(ss, o, 64);
        float sc = eff * 8.0f / fmaxf(sqrtf(ss), 1e-6f);
        qn[outbase] = f2bf(vr * sc);
    }
    {   // k
        float v = bf2f(qkvb[inbase + 1024]);
        float vp = __shfl_xor(v, 32, 64);
        float vr = (lane < 32) ? v * cs - vp * sn : v * cs + vp * sn;
        float ss = vr * vr;
#pragma unroll
        for (int o = 1; o < 64; o <<= 1) ss += __shfl_xor(ss, o, 64);
        float sc = eff / fmaxf(sqrtf(ss), 1e-6f);
        kn[outbase] = f2bf(vr * sc);
    }
}

// ---------- V transpose: qkvb v-part bf16 -> vt bf16 [B][H][64][2048] ----------
__global__ void k_vtrans(const short* __restrict__ qkvb, short* __restrict__ vt) {
    __shared__ short tile[64][72];
    int blk = blockIdx.x;
    int st = blk & 31, h = (blk >> 5) & 15, b = blk >> 9;
    int s0 = st * 64;
    int t = threadIdx.x;
    int sl = t >> 2, c0 = (t & 3) * 16;
    const short* src = qkvb + (size_t)(b * 2048 + s0 + sl) * 3072 + 2048 + h * 64 + c0;
    bf16x8 a0 = *(const bf16x8*)src;
    bf16x8 a1 = *(const bf16x8*)(src + 8);
#pragma unroll
    for (int jj = 0; jj < 8; jj++) { tile[sl][c0 + jj] = a0[jj]; tile[sl][c0 + 8 + jj] = a1[jj]; }
    __syncthreads();
    int hd = t >> 2, sc = (t & 3) * 16;
    bf16x8 p0, p1;
#pragma unroll
    for (int jj = 0; jj < 8; jj++) { p0[jj] = tile[sc + jj][hd]; p1[jj] = tile[sc + 8 + jj][hd]; }
    size_t obase = ((size_t)((b * 16 + h) * 64 + hd)) * 2048 + s0 + sc;
    *(bf16x8*)&vt[obase] = p0;
    *(bf16x8*)&vt[obase + 8] = p1;
}

// ---------- flash attention (causal), LDS-staged double-buffered KV tiles ----------
// grid (16, H, B); block 256 = 4 waves; wave w owns q rows [qb*128 + w*32, +32).
// K tile [64 keys][64 d], V^T tile [64 hd][64 keys] staged in LDS via global_load_lds
// with XOR-swizzled source (T2, rule 21); ds_read frags use the matching swizzle.
__launch_bounds__(256)
__global__ void k_attn(const short* __restrict__ qn, const short* __restrict__ kn,
                       const short* __restrict__ vt, short* __restrict__ ao) {
    __shared__ __align__(16) short Ks[2][64 * 64];   // 2 x 8 KB
    __shared__ __align__(16) short Vs[2][64 * 64];   // 2 x 8 KB
    __shared__ __align__(16) short Ps[4][32 * 64];   // 4 x 4 KB (per-wave P round-trip)
    const int t = threadIdx.x;
    const int w = t >> 6, lane = t & 63;
    const int qb = blockIdx.x, h = blockIdx.y, b = blockIdx.z;
    const int bh = b * 16 + h;
    const int qw = qb * 128 + w * 32;
    const int lr = lane & 15, lg = lane >> 4;
    const short* Qb = qn + (size_t)bh * 2048 * 64;
    const short* Kb = kn + (size_t)bh * 2048 * 64;
    const short* Vb = vt + (size_t)bh * 64 * 2048;
    char* pwc = (char*)&Ps[w][0];

    // Q fragments: [mi][kk], rows qw+mi*16+lr, d = kk*32 + lg*8
    bf16x8 qf[2][2];
#pragma unroll
    for (int mi = 0; mi < 2; mi++)
#pragma unroll
        for (int kk = 0; kk < 2; kk++)
            qf[mi][kk] = *(const bf16x8*)&Qb[(size_t)(qw + mi * 16 + lr) * 64 + kk * 32 + lg * 8];

    f32x4 oacc[2][4];
#pragma unroll
    for (int mi = 0; mi < 2; mi++)
#pragma unroll
        for (int ct = 0; ct < 4; ct++) oacc[mi][ct] = (f32x4){0.f, 0.f, 0.f, 0.f};
    float mrow[2][4], lsum[2][4];
#pragma unroll
    for (int mi = 0; mi < 2; mi++)
#pragma unroll
        for (int i = 0; i < 4; i++) { mrow[mi][i] = -3.0e38f; lsum[mi][i] = 0.0f; }

    const int nt = qb * 2 + 2;   // 64-wide tiles covering rows [0, qb*128+128)

    // stage tile (kbase) into buffer bi: each wave loads 16 rows of K and of V^T
#define STAGE_KV(bi, kbase)                                                          \
    {                                                                                \
        _Pragma("unroll")                                                            \
        for (int j = 0; j < 2; j++) {                                                \
            int row = w * 16 + j * 8 + (lane >> 3);                                  \
            int scol = (lane & 7) ^ (row & 7);                                       \
            gload16(Kb + (size_t)((kbase) + row) * 64 + scol * 8,                    \
                    &Ks[bi][(w * 16 + j * 8) * 64]);                                 \
            gload16(Vb + (size_t)row * 2048 + (kbase) + scol * 8,                    \
                    &Vs[bi][(w * 16 + j * 8) * 64]);                                 \
        }                                                                            \
    }

    STAGE_KV(0, 0);

    for (int kt = 0; kt < nt; kt++) {
        const int kbase = kt << 6;
        const int cur = kt & 1;
        __syncthreads();                      // drains vmcnt -> buf cur resident
        if (kt + 1 < nt) STAGE_KV(cur ^ 1, (kt + 1) << 6);

        // ---- QK^T: sv[mi][ni] = Q rows x K tile ----
        bf16x8 kf[4][2];
#pragma unroll
        for (int ni = 0; ni < 4; ni++)
#pragma unroll
            for (int kk = 0; kk < 2; kk++) {
                int row = ni * 16 + lr;
                kf[ni][kk] = *(const bf16x8*)&Ks[cur][row * 64 + (((kk * 4 + lg) ^ (row & 7)) << 3)];
            }
        f32x4 sv[2][4];
#pragma unroll
        for (int mi = 0; mi < 2; mi++)
#pragma unroll
            for (int ni = 0; ni < 4; ni++) {
                f32x4 s = (f32x4){0.f, 0.f, 0.f, 0.f};
                s = mfma16(qf[mi][0], kf[ni][0], s);
                s = mfma16(qf[mi][1], kf[ni][1], s);
                sv[mi][ni] = s;
            }
        // ---- causal mask (wave-uniform branch) ----
        if (kbase + 63 > qw) {
#pragma unroll
            for (int mi = 0; mi < 2; mi++)
#pragma unroll
                for (int ni = 0; ni < 4; ni++)
#pragma unroll
                    for (int i = 0; i < 4; i++) {
                        int qg = qw + mi * 16 + lg * 4 + i;
                        int kg = kbase + ni * 16 + lr;
                        if (kg > qg) sv[mi][ni][i] = -3.0e38f;
                    }
        }
        // ---- online softmax ----
#pragma unroll
        for (int mi = 0; mi < 2; mi++) {
            float mx[4];
#pragma unroll
            for (int i = 0; i < 4; i++)
                mx[i] = fmaxf(fmaxf(sv[mi][0][i], sv[mi][1][i]), fmaxf(sv[mi][2][i], sv[mi][3][i]));
#pragma unroll
            for (int o = 1; o < 16; o <<= 1)
#pragma unroll
                for (int i = 0; i < 4; i++)
                    mx[i] = fmaxf(mx[i], __shfl_xor(mx[i], o, 64));
            float al[4];
#pragma unroll
            for (int i = 0; i < 4; i++) {
                float mn = fmaxf(mrow[mi][i], mx[i]);
                al[i] = exp2f((mrow[mi][i] - mn) * 1.44269504f);
                mrow[mi][i] = mn;
            }
            float ps[4] = {0.f, 0.f, 0.f, 0.f};
#pragma unroll
            for (int ni = 0; ni < 4; ni++)
#pragma unroll
                for (int i = 0; i < 4; i++) {
                    float p = exp2f((sv[mi][ni][i] - mrow[mi][i]) * 1.44269504f);
                    sv[mi][ni][i] = p;          // reuse sv as P
                    ps[i] += p;
                }
#pragma unroll
            for (int o = 1; o < 16; o <<= 1)
#pragma unroll
                for (int i = 0; i < 4; i++)
                    ps[i] += __shfl_xor(ps[i], o, 64);
#pragma unroll
            for (int i = 0; i < 4; i++)
                lsum[mi][i] = lsum[mi][i] * al[i] + ps[i];
#pragma unroll
            for (int ct = 0; ct < 4; ct++)
#pragma unroll
                for (int i = 0; i < 4; i++)
                    oacc[mi][ct][i] *= al[i];
            // P: C-layout -> swizzled per-wave LDS
#pragma unroll
            for (int ni = 0; ni < 4; ni++)
#pragma unroll
                for (int i = 0; i < 4; i++) {
                    int row = mi * 16 + lg * 4 + i;
                    int col = ni * 16 + lr;
                    unsigned off = (unsigned)(row * 128 + col * 2) ^ ((unsigned)(row & 7) << 4);
                    *(short*)(pwc + off) = f2bf(sv[mi][ni][i]);
                }
        }
        // ---- PV: O += P x V^T ----
        bf16x8 pa[2][2];
#pragma unroll
        for (int mi = 0; mi < 2; mi++)
#pragma unroll
            for (int kk = 0; kk < 2; kk++) {
                int row = mi * 16 + lr;
                unsigned off = (unsigned)(row * 128 + kk * 64 + lg * 16) ^ ((unsigned)(row & 7) << 4);
                pa[mi][kk] = *(const bf16x8*)(pwc + off);
            }
        bf16x8 vf[4][2];
#pragma unroll
        for (int ct = 0; ct < 4; ct++)
#pragma unroll
            for (int kk = 0; kk < 2; kk++) {
                int row = ct * 16 + lr;
                vf[ct][kk] = *(const bf16x8*)&Vs[cur][row * 64 + (((kk * 4 + lg) ^ (row & 7)) << 3)];
            }
#pragma unroll
        for (int mi = 0; mi < 2; mi++)
#pragma unroll
            for (int ct = 0; ct < 4; ct++) {
                oacc[mi][ct] = mfma16(pa[mi][0], vf[ct][0], oacc[mi][ct]);
                oacc[mi][ct] = mfma16(pa[mi][1], vf[ct][1], oacc[mi][ct]);
            }
    }
#undef STAGE_KV

    short* aob = ao + ((size_t)(b * 2048 + qw) * 1024) + h * 64;
#pragma unroll
    for (int mi = 0; mi < 2; mi++) {
        float rl[4];
#pragma unroll
        for (int i = 0; i < 4; i++) rl[i] = 1.0f / lsum[mi][i];
#pragma unroll
        for (int ct = 0; ct < 4; ct++)
#pragma unroll
            for (int i = 0; i < 4; i++) {
                int q = mi * 16 + lg * 4 + i;
                aob[(size_t)q * 1024 + ct * 16 + lr] = f2bf(oacc[mi][ct][i] * rl[i]);
            }
    }
}

// ---------- residual + double cosine_norm (base/outf may alias: no restrict on them) ----------
__global__ void k_resnorm(const float* base, const float* __restrict__ pre,
                          const float* __restrict__ alpha, float* outf,
                          short* __restrict__ outb) {
    __shared__ float red1[4], red2[4];
    int row = blockIdx.x;
    int t = threadIdx.x;
    int w = t >> 6;
    const float4 p = *(const float4*)(pre + (size_t)row * 1024 + t * 4);
    float ss = p.x * p.x + p.y * p.y + p.z * p.z + p.w * p.w;
#pragma unroll
    for (int o = 1; o < 64; o <<= 1) ss += __shfl_xor(ss, o, 64);
    if ((t & 63) == 0) red1[w] = ss;
    __syncthreads();
    float inv1 = 1.0f / fmaxf(sqrtf(red1[0] + red1[1] + red1[2] + red1[3]), 1e-6f);
    const float4 bx = *(const float4*)(base + (size_t)row * 1024 + t * 4);
    const float4 av = *(const float4*)(alpha + t * 4);
    float4 tm;
    tm.x = bx.x + av.x * (p.x * inv1 - bx.x);
    tm.y = bx.y + av.y * (p.y * inv1 - bx.y);
    tm.z = bx.z + av.z * (p.z * inv1 - bx.z);
    tm.w = bx.w + av.w * (p.w * inv1 - bx.w);
    float ss2 = tm.x * tm.x + tm.y * tm.y + tm.z * tm.z + tm.w * tm.w;
#pragma unroll
    for (int o = 1; o < 64; o <<= 1) ss2 += __shfl_xor(ss2, o, 64);
    if ((t & 63) == 0) red2[w] = ss2;
    __syncthreads();
    float inv2 = 1.0f / fmaxf(sqrtf(red2[0] + red2[1] + red2[2] + red2[3]), 1e-6f);
    float4 hv;
    hv.x = tm.x * inv2; hv.y = tm.y * inv2; hv.z = tm.z * inv2; hv.w = tm.w * inv2;
    if (outf) *(float4*)(outf + (size_t)row * 1024 + t * 4) = hv;
    if (outb) {
        short4 o4;
        o4.x = f2bf(hv.x); o4.y = f2bf(hv.y); o4.z = f2bf(hv.z); o4.w = f2bf(hv.w);
        *(short4*)(outb + (size_t)row * 1024 + t * 4) = o4;
    }
}

// ---------- launch ----------
// Workspace layout (bytes), lifetime-overlaid; peak use = 76,152,832 B (72.6 MiB).
extern "C" void kernel_launch(void* const* d_in, const int* in_sizes, int n_in,
                              void* d_out, int out_size, void* d_ws, size_t ws_size,
                              hipStream_t stream) {
    (void)in_sizes; (void)n_in; (void)out_size; (void)ws_size;
    const float* x   = (const float*)d_in[0];
    const float* Wq  = (const float*)d_in[1];
    const float* Wk  = (const float*)d_in[2];
    const float* Wv  = (const float*)d_in[3];
    const float* Wo  = (const float*)d_in[4];
    const float* sqk = (const float*)d_in[5];
    const float* aA  = (const float*)d_in[6];
    const float* Wup = (const float*)d_in[7];
    const float* Wg  = (const float*)d_in[8];
    const float* Wd  = (const float*)d_in[9];
    const float* su  = (const float*)d_in[10];
    const float* sv  = (const float*)d_in[11];
    const float* aM  = (const float*)d_in[12];

    char* ws = (char*)d_ws;
    short* wqkvT  = (short*)(ws + 0);          // [3072][1024]
    short* woT    = (short*)(ws + 6291456);    // [1024][1024]
    short* wupT   = (short*)(ws + 8388608);    // [2752][1024]
    short* wgateT = (short*)(ws + 14024704);   // [2752][1024]
    short* wdownT = (short*)(ws + 19660800);   // [1024][2752]
    float* cost   = (float*)(ws + 25296896);
    float* sint   = (float*)(ws + 25559040);
    short* xbf    = (short*)(ws + 25821184);
    short* qkvb   = (short*)(ws + 34209792);   // [4096][3072] bf16
    short* qn     = (short*)(ws + 59375616);
    short* kn     = (short*)(ws + 67764224);
    short* vt     = (short*)(ws + 25821184);   // reuse xbf
    short* ao     = (short*)(ws + 34209792);   // reuse qkvb
    float* hA     = (float*)(ws + 42598400);
    float* h1f    = (float*)d_out;             // d_out doubles as h1 storage
    short* h1bf   = (short*)(ws + 25821184);   // reuse vt
    short* wmlp   = (short*)(ws + 34209792);   // reuse ao/hA: [4096][2752]
    float* hM     = (float*)(ws + 59375616);   // reuse qn/kn

    k_cvt_bf16<<<4096, 256, 0, stream>>>(x, xbf, 4194304);
    k_transpose_cvt<<<dim3(32, 32), 256, 0, stream>>>(Wq, wqkvT,           1024, 1024, 1024, 1024);
    k_transpose_cvt<<<dim3(32, 32), 256, 0, stream>>>(Wk, wqkvT + 1048576, 1024, 1024, 1024, 1024);
    k_transpose_cvt<<<dim3(32, 32), 256, 0, stream>>>(Wv, wqkvT + 2097152, 1024, 1024, 1024, 1024);
    k_transpose_cvt<<<dim3(32, 32), 256, 0, stream>>>(Wo, woT,             1024, 1024, 1024, 1024);
    k_transpose_cvt<<<dim3(86, 32), 256, 0, stream>>>(Wup, wupT,   1024, 2730, 1024, 2752);
    k_transpose_cvt<<<dim3(86, 32), 256, 0, stream>>>(Wg,  wgateT, 1024, 2730, 1024, 2752);
    k_transpose_cvt<<<dim3(32, 86), 256, 0, stream>>>(Wd,  wdownT, 2730, 1024, 2752, 1024);
    k_freqs<<<256, 256, 0, stream>>>(cost, sint);

    k_gemm128<1><<<dim3(32, 24), 256, 0, stream>>>(xbf, wqkvT, qkvb, 4096, 3072, 1024);
    k_rope<<<16384, 256, 0, stream>>>(qkvb, cost, sint, sqk, qn, kn);
    k_vtrans<<<1024, 256, 0, stream>>>(qkvb, vt);
    k_attn<<<dim3(16, 16, 2), 256, 0, stream>>>(qn, kn, vt, ao);
    k_gemm128<0><<<dim3(32, 8), 256, 0, stream>>>(ao, woT, hA, 4096, 1024, 1024);
    k_resnorm<<<4096, 256, 0, stream>>>(x, hA, aA, h1f, h1bf);
    k_gemm_dual<<<dim3(32, 43), 256, 0, stream>>>(h1bf, wupT, wgateT, su, sv, wmlp, 4096, 2752, 1024);
    k_gemm128<0><<<dim3(32, 8), 256, 0, stream>>>(wmlp, wdownT, hM, 4096, 1024, 2752);
    k_resnorm<<<4096, 256, 0, stream>>>(h1f, hM, aM, (float*)d_out, (short*)nullptr);
}

// Round 4
// 380.017 us; speedup vs baseline: 1.3322x; 1.0830x over previous
//
#include <hip/hip_runtime.h>
#include <math.h>

#define DEVI __device__ __forceinline__

typedef __attribute__((ext_vector_type(4))) float f32x4;
typedef __attribute__((ext_vector_type(8))) short bf16x8;

// ---------- helpers ----------
DEVI short f2bf(float f) {                    // f32 -> bf16 (RNE)
    union { float f; unsigned u; } v; v.f = f;
    unsigned r = v.u + 0x7fffu + ((v.u >> 16) & 1u);
    return (short)(r >> 16);
}
DEVI float bf2f(short s) {
    union { unsigned u; float f; } v; v.u = ((unsigned)(unsigned short)s) << 16;
    return v.f;
}

DEVI f32x4 mfma16(bf16x8 a, bf16x8 b, f32x4 c) {
    return __builtin_amdgcn_mfma_f32_16x16x32_bf16(a, b, c, 0, 0, 0);
}

DEVI void gload16(const short* g, short* l) {  // async global->LDS, 16B/lane
    __builtin_amdgcn_global_load_lds((__attribute__((address_space(1))) void*)(g),
                                     (__attribute__((address_space(3))) void*)(l),
                                     16, 0, 0);
}

// ---------- elementwise f32 -> bf16 ----------
__global__ void k_cvt_bf16(const float* __restrict__ in, short* __restrict__ out, int n) {
    int i = (blockIdx.x * blockDim.x + threadIdx.x) * 4;
    if (i >= n) return;
    float4 v = *(const float4*)(in + i);
    short4 o;
    o.x = f2bf(v.x); o.y = f2bf(v.y); o.z = f2bf(v.z); o.w = f2bf(v.w);
    *(short4*)(out + i) = o;
}

// ---------- transpose + convert: in f32 [R][C] -> out bf16 [Cpad][Rpad], zero pad ----------
__global__ void k_transpose_cvt(const float* __restrict__ in, short* __restrict__ out,
                                int R, int C, int Rpad, int Cpad) {
    __shared__ float tile[32][33];
    int c0 = blockIdx.x * 32;   // C-dim (out rows)
    int r0 = blockIdx.y * 32;   // R-dim (out cols)
    int tx = threadIdx.x & 31, ty = threadIdx.x >> 5;   // ty in [0,8)
#pragma unroll
    for (int i = 0; i < 4; i++) {
        int r = r0 + ty + 8 * i, c = c0 + tx;
        tile[ty + 8 * i][tx] = (r < R && c < C) ? in[(size_t)r * C + c] : 0.0f;
    }
    __syncthreads();
#pragma unroll
    for (int i = 0; i < 4; i++) {
        int oc = c0 + ty + 8 * i;   // out row
        int orr = r0 + tx;          // out col
        if (oc < Cpad && orr < Rpad)
            out[(size_t)oc * Rpad + orr] = f2bf(tile[tx][ty + 8 * i]);
    }
}

// ---------- RoPE freq tables (f64 for reference fidelity) ----------
__global__ void k_freqs(float* __restrict__ cost, float* __restrict__ sint) {
    int i = blockIdx.x * blockDim.x + threadIdx.x;   // [0, 2048*32)
    int s = i >> 5, j = i & 31;
    double inv = pow(10000.0, -(double)j / 32.0);
    double f = (double)s * inv;
    cost[i] = (float)cos(f);
    sint[i] = (float)sin(f);
}

// ---------- GEMM: C = A bf16[M][K] * BT bf16[N][K], 128x128x32; OUT_BF16 selects C dtype ----------
template <int OUT_BF16>
__launch_bounds__(256)
__global__ void k_gemm128(const short* __restrict__ A, const short* __restrict__ BT,
                          void* __restrict__ Cv, int M, int N, int K) {
    __shared__ __align__(16) short As[128 * 32];
    __shared__ __align__(16) short Bs[128 * 32];
    const int t = threadIdx.x;
    const int w = t >> 6;
    const int lane = t & 63;
    const int lr = lane & 15, lg = lane >> 4;
    const int m0 = blockIdx.x * 128, n0 = blockIdx.y * 128;
    const int wr = (w >> 1) * 64, wc = (w & 1) * 64;

    f32x4 acc[4][4];
#pragma unroll
    for (int m = 0; m < 4; m++)
#pragma unroll
        for (int n = 0; n < 4; n++)
            acc[m][n] = (f32x4){0.f, 0.f, 0.f, 0.f};

    const int nk = K >> 5;
    for (int kt = 0; kt < nk; kt++) {
        const int k0 = kt << 5;
#pragma unroll
        for (int j = 0; j < 2; j++) {
            int c = t + (j << 8);
            int row = c >> 2, col = (c & 3) << 3;
            gload16(A + (size_t)(m0 + row) * K + k0 + col,
                    As + (size_t)(w * 64 + (j << 8)) * 8);
            gload16(BT + (size_t)(n0 + row) * K + k0 + col,
                    Bs + (size_t)(w * 64 + (j << 8)) * 8);
        }
        __syncthreads();
        bf16x8 af[4], bfr[4];
#pragma unroll
        for (int m = 0; m < 4; m++)
            af[m] = *(const bf16x8*)&As[(wr + m * 16 + lr) * 32 + lg * 8];
#pragma unroll
        for (int n = 0; n < 4; n++)
            bfr[n] = *(const bf16x8*)&Bs[(wc + n * 16 + lr) * 32 + lg * 8];
#pragma unroll
        for (int m = 0; m < 4; m++)
#pragma unroll
            for (int n = 0; n < 4; n++)
                acc[m][n] = mfma16(af[m], bfr[n], acc[m][n]);
        __syncthreads();
    }
#pragma unroll
    for (int m = 0; m < 4; m++)
#pragma unroll
        for (int n = 0; n < 4; n++) {
            int row = m0 + wr + m * 16 + lg * 4;
            int col = n0 + wc + n * 16 + lr;
#pragma unroll
            for (int i = 0; i < 4; i++) {
                if (OUT_BF16)
                    ((short*)Cv)[(size_t)(row + i) * N + col] = f2bf(acc[m][n][i]);
                else
                    ((float*)Cv)[(size_t)(row + i) * N + col] = acc[m][n][i];
            }
        }
}

// ---------- dual GEMM + SwiGLU: w = (A*BTu)*s_u * silu((A*BTg)*s_v*32), bf16 out ----------
__launch_bounds__(256)
__global__ void k_gemm_dual(const short* __restrict__ A, const short* __restrict__ BTu,
                            const short* __restrict__ BTg, const float* __restrict__ s_u,
                            const float* __restrict__ s_v, short* __restrict__ Wout,
                            int M, int N, int K) {
    __shared__ __align__(16) short As[128 * 32];
    __shared__ __align__(16) short Bus[64 * 32];
    __shared__ __align__(16) short Bgs[64 * 32];
    const int t = threadIdx.x;
    const int w = t >> 6;
    const int lane = t & 63;
    const int lr = lane & 15, lg = lane >> 4;
    const int m0 = blockIdx.x * 128, n0 = blockIdx.y * 64;
    const int wr = (w >> 1) * 64, wc = (w & 1) * 32;

    f32x4 aU[4][2], aG[4][2];
#pragma unroll
    for (int m = 0; m < 4; m++)
#pragma unroll
        for (int n = 0; n < 2; n++) {
            aU[m][n] = (f32x4){0.f, 0.f, 0.f, 0.f};
            aG[m][n] = (f32x4){0.f, 0.f, 0.f, 0.f};
        }

    const int nk = K >> 5;
    for (int kt = 0; kt < nk; kt++) {
        const int k0 = kt << 5;
#pragma unroll
        for (int j = 0; j < 2; j++) {
            int c = t + (j << 8);
            gload16(A + (size_t)(m0 + (c >> 2)) * K + k0 + ((c & 3) << 3),
                    As + (size_t)(w * 64 + (j << 8)) * 8);
        }
        {
            int row = t >> 2, col = (t & 3) << 3;
            gload16(BTu + (size_t)(n0 + row) * K + k0 + col, Bus + (size_t)(w * 64) * 8);
            gload16(BTg + (size_t)(n0 + row) * K + k0 + col, Bgs + (size_t)(w * 64) * 8);
        }
        __syncthreads();
        bf16x8 af[4], bu[2], bg[2];
#pragma unroll
        for (int m = 0; m < 4; m++)
            af[m] = *(const bf16x8*)&As[(wr + m * 16 + lr) * 32 + lg * 8];
#pragma unroll
        for (int n = 0; n < 2; n++) {
            bu[n] = *(const bf16x8*)&Bus[(wc + n * 16 + lr) * 32 + lg * 8];
            bg[n] = *(const bf16x8*)&Bgs[(wc + n * 16 + lr) * 32 + lg * 8];
        }
#pragma unroll
        for (int m = 0; m < 4; m++)
#pragma unroll
            for (int n = 0; n < 2; n++) {
                aU[m][n] = mfma16(af[m], bu[n], aU[m][n]);
                aG[m][n] = mfma16(af[m], bg[n], aG[m][n]);
            }
        __syncthreads();
    }
#pragma unroll
    for (int m = 0; m < 4; m++)
#pragma unroll
        for (int n = 0; n < 2; n++) {
            int col = n0 + wc + n * 16 + lr;
            int jc = col < 2730 ? col : 0;
            float su = s_u[jc];
            float sg = s_v[jc] * 32.0f;
#pragma unroll
            for (int i = 0; i < 4; i++) {
                int row = m0 + wr + m * 16 + lg * 4 + i;
                float uu = aU[m][n][i] * su;
                float vv = aG[m][n][i] * sg;
                float sig = 1.0f / (1.0f + expf(-vv));
                Wout[(size_t)row * N + col] = f2bf(uu * vv * sig);
            }
        }
}

// ---------- RoPE + cosine_norm for q,k. qkvb bf16 [4096][3072] -> qn,kn bf16 [B][H][S][64] ----------
__global__ void k_rope(const short* __restrict__ qkvb, const float* __restrict__ cost,
                       const float* __restrict__ sint, const float* __restrict__ sqk,
                       short* __restrict__ qn, short* __restrict__ kn) {
    int wid = blockIdx.x * 4 + (threadIdx.x >> 6);   // [0, 65536)
    int lane = threadIdx.x & 63;
    int h = wid & 15;
    int s = (wid >> 4) & 2047;
    int b = wid >> 15;
    int row = b * 2048 + s;
    int j = lane & 31;
    float cs = cost[s * 32 + j];
    float sn = sint[s * 32 + j];
    float eff = sqk[h * 64 + lane] * 32.0f;          // s_qk * sqrt(DIM)
    size_t inbase = (size_t)row * 3072 + h * 64 + lane;
    size_t outbase = ((size_t)(b * 16 + h) * 2048 + s) * 64 + lane;
    {   // q  (extra *8 = sqrt(HD) logit scale folded in)
        float v = bf2f(qkvb[inbase]);
        float vp = __shfl_xor(v, 32, 64);
        float vr = (lane < 32) ? v * cs - vp * sn : v * cs + vp * sn;
        float ss = vr * vr;
#pragma unroll
        for (int o = 1; o < 64; o <<= 1) ss += __shfl_xor(ss, o, 64);
        float sc = eff * 8.0f / fmaxf(sqrtf(ss), 1e-6f);
        qn[outbase] = f2bf(vr * sc);
    }
    {   // k
        float v = bf2f(qkvb[inbase + 1024]);
        float vp = __shfl_xor(v, 32, 64);
        float vr = (lane < 32) ? v * cs - vp * sn : v * cs + vp * sn;
        float ss = vr * vr;
#pragma unroll
        for (int o = 1; o < 64; o <<= 1) ss += __shfl_xor(ss, o, 64);
        float sc = eff / fmaxf(sqrtf(ss), 1e-6f);
        kn[outbase] = f2bf(vr * sc);
    }
}

// ---------- V transpose: qkvb v-part bf16 -> vt bf16 [B][H][64][2048] ----------
__global__ void k_vtrans(const short* __restrict__ qkvb, short* __restrict__ vt) {
    __shared__ short tile[64][72];
    int blk = blockIdx.x;
    int st = blk & 31, h = (blk >> 5) & 15, b = blk >> 9;
    int s0 = st * 64;
    int t = threadIdx.x;
    int sl = t >> 2, c0 = (t & 3) * 16;
    const short* src = qkvb + (size_t)(b * 2048 + s0 + sl) * 3072 + 2048 + h * 64 + c0;
    bf16x8 a0 = *(const bf16x8*)src;
    bf16x8 a1 = *(const bf16x8*)(src + 8);
#pragma unroll
    for (int jj = 0; jj < 8; jj++) { tile[sl][c0 + jj] = a0[jj]; tile[sl][c0 + 8 + jj] = a1[jj]; }
    __syncthreads();
    int hd = t >> 2, sc = (t & 3) * 16;
    bf16x8 p0, p1;
#pragma unroll
    for (int jj = 0; jj < 8; jj++) { p0[jj] = tile[sc + jj][hd]; p1[jj] = tile[sc + 8 + jj][hd]; }
    size_t obase = ((size_t)((b * 16 + h) * 64 + hd)) * 2048 + s0 + sc;
    *(bf16x8*)&vt[obase] = p0;
    *(bf16x8*)&vt[obase + 8] = p1;
}

// ---------- flash attention (causal), static-max softmax, split-K x2, LPT order ----------
// nGPT: q,k cosine-normed, eff_s_qk = 1 -> logits = 8*cos(theta) in [-8,8]; use static max 9.
// grid (32,16,2): x encodes (qb,half) heaviest-first: qb = 15-(x>>1), hf = x&1.
// Block: 4 waves x 32 q-rows = 128 rows. Tiles [hf*(qb+1), (hf+1)*(qb+1)) of 64 keys.
// Outputs UNNORMALIZED partial O (bf16) + partial row-sum lsum (f32); k_comb normalizes.
__launch_bounds__(256)
__global__ void k_attn(const short* __restrict__ qn, const short* __restrict__ kn,
                       const short* __restrict__ vt, short* __restrict__ opart,
                       float* __restrict__ lsump) {
    __shared__ __align__(16) short Ks[2][64 * 64];   // 2 x 8 KB
    __shared__ __align__(16) short Vs[2][64 * 64];   // 2 x 8 KB
    __shared__ __align__(16) short Ps[4][32 * 64];   // 4 x 4 KB
    const int t = threadIdx.x;
    const int w = t >> 6, lane = t & 63;
    const int qb = 15 - (int)(blockIdx.x >> 1), hf = blockIdx.x & 1;
    const int h = blockIdx.y, b = blockIdx.z;
    const int bh = b * 16 + h;
    const int qw = qb * 128 + w * 32;
    const int lr = lane & 15, lg = lane >> 4;
    const short* Qb = qn + (size_t)bh * 2048 * 64;
    const short* Kb = kn + (size_t)bh * 2048 * 64;
    const short* Vb = vt + (size_t)bh * 64 * 2048;
    char* pwc = (char*)&Ps[w][0];

    bf16x8 qf[2][2];
#pragma unroll
    for (int mi = 0; mi < 2; mi++)
#pragma unroll
        for (int kk = 0; kk < 2; kk++)
            qf[mi][kk] = *(const bf16x8*)&Qb[(size_t)(qw + mi * 16 + lr) * 64 + kk * 32 + lg * 8];

    f32x4 oacc[2][4];
#pragma unroll
    for (int mi = 0; mi < 2; mi++)
#pragma unroll
        for (int ct = 0; ct < 4; ct++) oacc[mi][ct] = (f32x4){0.f, 0.f, 0.f, 0.f};
    float psum[2][4];
#pragma unroll
    for (int mi = 0; mi < 2; mi++)
#pragma unroll
        for (int i = 0; i < 4; i++) psum[mi][i] = 0.0f;

    const int kt0 = hf * (qb + 1), kt1 = kt0 + qb + 1;

#define STAGE_KV(bi, kbase)                                                          \
    {                                                                                \
        _Pragma("unroll")                                                            \
        for (int j = 0; j < 2; j++) {                                                \
            int row = w * 16 + j * 8 + (lane >> 3);                                  \
            int scol = (lane & 7) ^ (row & 7);                                       \
            gload16(Kb + (size_t)((kbase) + row) * 64 + scol * 8,                    \
                    &Ks[bi][(w * 16 + j * 8) * 64]);                                 \
            gload16(Vb + (size_t)row * 2048 + (kbase) + scol * 8,                    \
                    &Vs[bi][(w * 16 + j * 8) * 64]);                                 \
        }                                                                            \
    }

    STAGE_KV(0, kt0 << 6);

    for (int kt = kt0; kt < kt1; kt++) {
        const int kbase = kt << 6;
        const int cur = (kt - kt0) & 1;
        __syncthreads();                      // drains vmcnt -> buf cur resident
        if (kt + 1 < kt1) STAGE_KV(cur ^ 1, (kt + 1) << 6);

        // ---- QK^T ----
        bf16x8 kf[4][2];
#pragma unroll
        for (int ni = 0; ni < 4; ni++)
#pragma unroll
            for (int kk = 0; kk < 2; kk++) {
                int row = ni * 16 + lr;
                kf[ni][kk] = *(const bf16x8*)&Ks[cur][row * 64 + (((kk * 4 + lg) ^ (row & 7)) << 3)];
            }
        f32x4 sv[2][4];
#pragma unroll
        for (int mi = 0; mi < 2; mi++)
#pragma unroll
            for (int ni = 0; ni < 4; ni++) {
                f32x4 s = (f32x4){0.f, 0.f, 0.f, 0.f};
                s = mfma16(qf[mi][0], kf[ni][0], s);
                s = mfma16(qf[mi][1], kf[ni][1], s);
                sv[mi][ni] = s;
            }
        // ---- causal mask (wave-uniform branch) ----
        if (kbase + 63 > qw) {
#pragma unroll
            for (int mi = 0; mi < 2; mi++)
#pragma unroll
                for (int ni = 0; ni < 4; ni++)
#pragma unroll
                    for (int i = 0; i < 4; i++) {
                        int qg = qw + mi * 16 + lg * 4 + i;
                        int kg = kbase + ni * 16 + lr;
                        if (kg > qg) sv[mi][ni][i] = -3.0e38f;
                    }
        }
        // ---- static-max softmax: p = 2^((s-9)*log2e), accumulate per-lane sums ----
#pragma unroll
        for (int mi = 0; mi < 2; mi++) {
#pragma unroll
            for (int ni = 0; ni < 4; ni++)
#pragma unroll
                for (int i = 0; i < 4; i++) {
                    float p = exp2f((sv[mi][ni][i] - 9.0f) * 1.44269504f);
                    sv[mi][ni][i] = p;
                    psum[mi][i] += p;
                }
            // P: C-layout -> swizzled per-wave LDS
#pragma unroll
            for (int ni = 0; ni < 4; ni++)
#pragma unroll
                for (int i = 0; i < 4; i++) {
                    int row = mi * 16 + lg * 4 + i;
                    int col = ni * 16 + lr;
                    unsigned off = (unsigned)(row * 128 + col * 2) ^ ((unsigned)(row & 7) << 4);
                    *(short*)(pwc + off) = f2bf(sv[mi][ni][i]);
                }
        }
        // ---- PV: O += P x V^T (unnormalized, no rescale) ----
        bf16x8 pa[2][2];
#pragma unroll
        for (int mi = 0; mi < 2; mi++)
#pragma unroll
            for (int kk = 0; kk < 2; kk++) {
                int row = mi * 16 + lr;
                unsigned off = (unsigned)(row * 128 + kk * 64 + lg * 16) ^ ((unsigned)(row & 7) << 4);
                pa[mi][kk] = *(const bf16x8*)(pwc + off);
            }
        bf16x8 vf[4][2];
#pragma unroll
        for (int ct = 0; ct < 4; ct++)
#pragma unroll
            for (int kk = 0; kk < 2; kk++) {
                int row = ct * 16 + lr;
                vf[ct][kk] = *(const bf16x8*)&Vs[cur][row * 64 + (((kk * 4 + lg) ^ (row & 7)) << 3)];
            }
#pragma unroll
        for (int mi = 0; mi < 2; mi++)
#pragma unroll
            for (int ct = 0; ct < 4; ct++) {
                oacc[mi][ct] = mfma16(pa[mi][0], vf[ct][0], oacc[mi][ct]);
                oacc[mi][ct] = mfma16(pa[mi][1], vf[ct][1], oacc[mi][ct]);
            }
    }
#undef STAGE_KV

    // ---- one-time lsum reduce across the 16 lr lanes ----
#pragma unroll
    for (int o = 1; o < 16; o <<= 1)
#pragma unroll
        for (int mi = 0; mi < 2; mi++)
#pragma unroll
            for (int i = 0; i < 4; i++)
                psum[mi][i] += __shfl_xor(psum[mi][i], o, 64);

    short* aob = opart + (size_t)hf * 4096 * 1024 + ((size_t)(b * 2048 + qw) * 1024) + h * 64;
#pragma unroll
    for (int mi = 0; mi < 2; mi++)
#pragma unroll
        for (int ct = 0; ct < 4; ct++)
#pragma unroll
            for (int i = 0; i < 4; i++) {
                int q = mi * 16 + lg * 4 + i;
                aob[(size_t)q * 1024 + ct * 16 + lr] = f2bf(oacc[mi][ct][i]);
            }
    if (lr == 0) {
#pragma unroll
        for (int mi = 0; mi < 2; mi++)
#pragma unroll
            for (int i = 0; i < 4; i++)
                lsump[hf * 65536 + bh * 2048 + qw + mi * 16 + lg * 4 + i] = psum[mi][i];
    }
}

// ---------- combine split-K partials: ao = (O0+O1)/(l0+l1), bf16 ----------
__global__ void k_comb(const short* __restrict__ op, const float* __restrict__ ls,
                       short* __restrict__ ao) {
    int i = (blockIdx.x * 256 + threadIdx.x) * 4;     // over 4096*1024
    int row = i >> 10, col = i & 1023;
    int idx = ((row >> 11) * 16 + (col >> 6)) * 2048 + (row & 2047);
    float rl = 1.0f / (ls[idx] + ls[65536 + idx]);
    short4 a = *(const short4*)(op + i);
    short4 c = *(const short4*)(op + 4194304 + i);
    short4 o;
    o.x = f2bf((bf2f(a.x) + bf2f(c.x)) * rl);
    o.y = f2bf((bf2f(a.y) + bf2f(c.y)) * rl);
    o.z = f2bf((bf2f(a.z) + bf2f(c.z)) * rl);
    o.w = f2bf((bf2f(a.w) + bf2f(c.w)) * rl);
    *(short4*)(ao + i) = o;
}

// ---------- residual + double cosine_norm (base/outf may alias: no restrict on them) ----------
__global__ void k_resnorm(const float* base, const float* __restrict__ pre,
                          const float* __restrict__ alpha, float* outf,
                          short* __restrict__ outb) {
    __shared__ float red1[4], red2[4];
    int row = blockIdx.x;
    int t = threadIdx.x;
    int w = t >> 6;
    const float4 p = *(const float4*)(pre + (size_t)row * 1024 + t * 4);
    float ss = p.x * p.x + p.y * p.y + p.z * p.z + p.w * p.w;
#pragma unroll
    for (int o = 1; o < 64; o <<= 1) ss += __shfl_xor(ss, o, 64);
    if ((t & 63) == 0) red1[w] = ss;
    __syncthreads();
    float inv1 = 1.0f / fmaxf(sqrtf(red1[0] + red1[1] + red1[2] + red1[3]), 1e-6f);
    const float4 bx = *(const float4*)(base + (size_t)row * 1024 + t * 4);
    const float4 av = *(const float4*)(alpha + t * 4);
    float4 tm;
    tm.x = bx.x + av.x * (p.x * inv1 - bx.x);
    tm.y = bx.y + av.y * (p.y * inv1 - bx.y);
    tm.z = bx.z + av.z * (p.z * inv1 - bx.z);
    tm.w = bx.w + av.w * (p.w * inv1 - bx.w);
    float ss2 = tm.x * tm.x + tm.y * tm.y + tm.z * tm.z + tm.w * tm.w;
#pragma unroll
    for (int o = 1; o < 64; o <<= 1) ss2 += __shfl_xor(ss2, o, 64);
    if ((t & 63) == 0) red2[w] = ss2;
    __syncthreads();
    float inv2 = 1.0f / fmaxf(sqrtf(red2[0] + red2[1] + red2[2] + red2[3]), 1e-6f);
    float4 hv;
    hv.x = tm.x * inv2; hv.y = tm.y * inv2; hv.z = tm.z * inv2; hv.w = tm.w * inv2;
    if (outf) *(float4*)(outf + (size_t)row * 1024 + t * 4) = hv;
    if (outb) {
        short4 o4;
        o4.x = f2bf(hv.x); o4.y = f2bf(hv.y); o4.z = f2bf(hv.z); o4.w = f2bf(hv.w);
        *(short4*)(outb + (size_t)row * 1024 + t * 4) = o4;
    }
}

// ---------- launch ----------
// Workspace (lifetime-overlaid, peak 76,152,832 B = known-safe):
//  [0, 25821184)   weights bf16^T + rope tables          (whole launch)
//  B 25821184      xbf(#1-#4) -> vt(#6-#7) -> h1bf(#10-#11)              8 MB
//  C 34209792      qkvb(#4-#6) 24MB -> opart[2](#7-#8) 16MB -> hA(#9-#10) 16MB -> wmlp(#11-#12) 22.5MB
//  50987008        lsum (#7-#8) 0.5MB
//  52035584        ao (#8-#9) 8MB
//  59375616        qn(#5-#7) -> hM(#12-#13) 16MB
//  67764224        kn(#5-#7)
extern "C" void kernel_launch(void* const* d_in, const int* in_sizes, int n_in,
                              void* d_out, int out_size, void* d_ws, size_t ws_size,
                              hipStream_t stream) {
    (void)in_sizes; (void)n_in; (void)out_size; (void)ws_size;
    const float* x   = (const float*)d_in[0];
    const float* Wq  = (const float*)d_in[1];
    const float* Wk  = (const float*)d_in[2];
    const float* Wv  = (const float*)d_in[3];
    const float* Wo  = (const float*)d_in[4];
    const float* sqk = (const float*)d_in[5];
    const float* aA  = (const float*)d_in[6];
    const float* Wup = (const float*)d_in[7];
    const float* Wg  = (const float*)d_in[8];
    const float* Wd  = (const float*)d_in[9];
    const float* su  = (const float*)d_in[10];
    const float* sv  = (const float*)d_in[11];
    const float* aM  = (const float*)d_in[12];

    char* ws = (char*)d_ws;
    short* wqkvT  = (short*)(ws + 0);          // [3072][1024]
    short* woT    = (short*)(ws + 6291456);    // [1024][1024]
    short* wupT   = (short*)(ws + 8388608);    // [2752][1024]
    short* wgateT = (short*)(ws + 14024704);   // [2752][1024]
    short* wdownT = (short*)(ws + 19660800);   // [1024][2752]
    float* cost   = (float*)(ws + 25296896);
    float* sint   = (float*)(ws + 25559040);
    short* xbf    = (short*)(ws + 25821184);
    short* qkvb   = (short*)(ws + 34209792);   // [4096][3072] bf16
    short* qn     = (short*)(ws + 59375616);
    short* kn     = (short*)(ws + 67764224);
    short* vt     = (short*)(ws + 25821184);   // reuse xbf
    short* opart  = (short*)(ws + 34209792);   // reuse qkvb: [2][4096][1024] bf16
    float* lsum   = (float*)(ws + 50987008);   // [2][32][2048] f32
    short* ao     = (short*)(ws + 52035584);   // [4096][1024] bf16
    float* hA     = (float*)(ws + 34209792);   // reuse opart after comb
    float* h1f    = (float*)d_out;             // d_out doubles as h1 storage
    short* h1bf   = (short*)(ws + 25821184);   // reuse vt
    short* wmlp   = (short*)(ws + 34209792);   // reuse hA: [4096][2752]
    float* hM     = (float*)(ws + 59375616);   // reuse qn/kn

    k_cvt_bf16<<<4096, 256, 0, stream>>>(x, xbf, 4194304);
    k_transpose_cvt<<<dim3(32, 32), 256, 0, stream>>>(Wq, wqkvT,           1024, 1024, 1024, 1024);
    k_transpose_cvt<<<dim3(32, 32), 256, 0, stream>>>(Wk, wqkvT + 1048576, 1024, 1024, 1024, 1024);
    k_transpose_cvt<<<dim3(32, 32), 256, 0, stream>>>(Wv, wqkvT + 2097152, 1024, 1024, 1024, 1024);
    k_transpose_cvt<<<dim3(32, 32), 256, 0, stream>>>(Wo, woT,             1024, 1024, 1024, 1024);
    k_transpose_cvt<<<dim3(86, 32), 256, 0, stream>>>(Wup, wupT,   1024, 2730, 1024, 2752);
    k_transpose_cvt<<<dim3(86, 32), 256, 0, stream>>>(Wg,  wgateT, 1024, 2730, 1024, 2752);
    k_transpose_cvt<<<dim3(32, 86), 256, 0, stream>>>(Wd,  wdownT, 2730, 1024, 2752, 1024);
    k_freqs<<<256, 256, 0, stream>>>(cost, sint);

    k_gemm128<1><<<dim3(32, 24), 256, 0, stream>>>(xbf, wqkvT, qkvb, 4096, 3072, 1024);
    k_rope<<<16384, 256, 0, stream>>>(qkvb, cost, sint, sqk, qn, kn);
    k_vtrans<<<1024, 256, 0, stream>>>(qkvb, vt);
    k_attn<<<dim3(32, 16, 2), 256, 0, stream>>>(qn, kn, vt, opart, lsum);
    k_comb<<<4096, 256, 0, stream>>>(opart, lsum, ao);
    k_gemm128<0><<<dim3(32, 8), 256, 0, stream>>>(ao, woT, hA, 4096, 1024, 1024);
    k_resnorm<<<4096, 256, 0, stream>>>(x, hA, aA, h1f, h1bf);
    k_gemm_dual<<<dim3(32, 43), 256, 0, stream>>>(h1bf, wupT, wgateT, su, sv, wmlp, 4096, 2752, 1024);
    k_gemm128<0><<<dim3(32, 8), 256, 0, stream>>>(wmlp, wdownT, hM, 4096, 1024, 2752);
    k_resnorm<<<4096, 256, 0, stream>>>(h1f, hM, aM, (float*)d_out, (short*)nullptr);
}

// Round 5
// 370.376 us; speedup vs baseline: 1.3668x; 1.0260x over previous
//
#include <hip/hip_runtime.h>
#include <math.h>

#define DEVI __device__ __forceinline__

typedef __attribute__((ext_vector_type(4))) float f32x4;
typedef __attribute__((ext_vector_type(8))) short bf16x8;

// ---------- helpers ----------
DEVI short f2bf(float f) {                    // f32 -> bf16 (RNE)
    union { float f; unsigned u; } v; v.f = f;
    unsigned r = v.u + 0x7fffu + ((v.u >> 16) & 1u);
    return (short)(r >> 16);
}
DEVI float bf2f(short s) {
    union { unsigned u; float f; } v; v.u = ((unsigned)(unsigned short)s) << 16;
    return v.f;
}

DEVI f32x4 mfma16(bf16x8 a, bf16x8 b, f32x4 c) {
    return __builtin_amdgcn_mfma_f32_16x16x32_bf16(a, b, c, 0, 0, 0);
}

DEVI void gload16(const short* g, short* l) {  // async global->LDS, 16B/lane
    __builtin_amdgcn_global_load_lds((__attribute__((address_space(1))) void*)(g),
                                     (__attribute__((address_space(3))) void*)(l),
                                     16, 0, 0);
}

// ---------- elementwise f32 -> bf16 ----------
__global__ void k_cvt_bf16(const float* __restrict__ in, short* __restrict__ out, int n) {
    int i = (blockIdx.x * blockDim.x + threadIdx.x) * 4;
    if (i >= n) return;
    float4 v = *(const float4*)(in + i);
    short4 o;
    o.x = f2bf(v.x); o.y = f2bf(v.y); o.z = f2bf(v.z); o.w = f2bf(v.w);
    *(short4*)(out + i) = o;
}

// ---------- transpose + convert: in f32 [R][C] -> out bf16 rows (c*rmul+radd), zero pad ----------
__global__ void k_transpose_cvt(const float* __restrict__ in, short* __restrict__ out,
                                int R, int C, int Rpad, int Cpad, int rmul, int radd) {
    __shared__ float tile[32][33];
    int c0 = blockIdx.x * 32;   // C-dim (out rows)
    int r0 = blockIdx.y * 32;   // R-dim (out cols)
    int tx = threadIdx.x & 31, ty = threadIdx.x >> 5;   // ty in [0,8)
#pragma unroll
    for (int i = 0; i < 4; i++) {
        int r = r0 + ty + 8 * i, c = c0 + tx;
        tile[ty + 8 * i][tx] = (r < R && c < C) ? in[(size_t)r * C + c] : 0.0f;
    }
    __syncthreads();
#pragma unroll
    for (int i = 0; i < 4; i++) {
        int oc = c0 + ty + 8 * i;   // out row (pre-interleave)
        int orr = r0 + tx;          // out col
        if (oc < Cpad && orr < Rpad)
            out[(size_t)(oc * rmul + radd) * Rpad + orr] = f2bf(tile[tx][ty + 8 * i]);
    }
}

// ---------- RoPE freq tables (f64 for reference fidelity) ----------
__global__ void k_freqs(float* __restrict__ cost, float* __restrict__ sint) {
    int i = blockIdx.x * blockDim.x + threadIdx.x;   // [0, 2048*32)
    int s = i >> 5, j = i & 31;
    double inv = pow(10000.0, -(double)j / 32.0);
    double f = (double)s * inv;
    cost[i] = (float)cos(f);
    sint[i] = (float)sin(f);
}

// ---------- GEMM: C = A bf16[M][K] * BT bf16[N][K], 128x128x32 ----------
// EPI: 0 = f32 out, 1 = bf16 out, 2 = SwiGLU-interleaved: B rows alternate up/gate,
//      out col j=col/2, w = (u*s_u[j]) * silu(g*s_v[j]*32), bf16 out stride N/2.
template <int EPI>
__launch_bounds__(256)
__global__ void k_gemm128(const short* __restrict__ A, const short* __restrict__ BT,
                          void* __restrict__ Cv, int M, int N, int K,
                          const float* __restrict__ s_u, const float* __restrict__ s_v) {
    __shared__ __align__(16) short As[128 * 32];
    __shared__ __align__(16) short Bs[128 * 32];
    const int t = threadIdx.x;
    const int w = t >> 6;
    const int lane = t & 63;
    const int lr = lane & 15, lg = lane >> 4;
    const int m0 = blockIdx.x * 128, n0 = blockIdx.y * 128;
    const int wr = (w >> 1) * 64, wc = (w & 1) * 64;

    f32x4 acc[4][4];
#pragma unroll
    for (int m = 0; m < 4; m++)
#pragma unroll
        for (int n = 0; n < 4; n++)
            acc[m][n] = (f32x4){0.f, 0.f, 0.f, 0.f};

    const int nk = K >> 5;
    for (int kt = 0; kt < nk; kt++) {
        const int k0 = kt << 5;
#pragma unroll
        for (int j = 0; j < 2; j++) {
            int c = t + (j << 8);
            int row = c >> 2, col = (c & 3) << 3;
            gload16(A + (size_t)(m0 + row) * K + k0 + col,
                    As + (size_t)(w * 64 + (j << 8)) * 8);
            gload16(BT + (size_t)(n0 + row) * K + k0 + col,
                    Bs + (size_t)(w * 64 + (j << 8)) * 8);
        }
        __syncthreads();
        bf16x8 af[4], bfr[4];
#pragma unroll
        for (int m = 0; m < 4; m++)
            af[m] = *(const bf16x8*)&As[(wr + m * 16 + lr) * 32 + lg * 8];
#pragma unroll
        for (int n = 0; n < 4; n++)
            bfr[n] = *(const bf16x8*)&Bs[(wc + n * 16 + lr) * 32 + lg * 8];
#pragma unroll
        for (int m = 0; m < 4; m++)
#pragma unroll
            for (int n = 0; n < 4; n++)
                acc[m][n] = mfma16(af[m], bfr[n], acc[m][n]);
        __syncthreads();
    }
#pragma unroll
    for (int m = 0; m < 4; m++)
#pragma unroll
        for (int n = 0; n < 4; n++) {
            int row = m0 + wr + m * 16 + lg * 4;
            int col = n0 + wc + n * 16 + lr;
            if (EPI == 2) {
                int j = col >> 1;
                int jc = j < 2730 ? j : 2729;
                float su = s_u[jc];
                float sg = s_v[jc] * 32.0f;
#pragma unroll
                for (int i = 0; i < 4; i++) {
                    float own = acc[m][n][i];
                    float oth = __shfl_xor(own, 1, 64);
                    float u = (lr & 1) ? oth : own;
                    float g = (lr & 1) ? own : oth;
                    float uu = u * su;
                    float vv = g * sg;
                    float wv = uu * vv / (1.0f + expf(-vv));
                    if (!(lr & 1))
                        ((short*)Cv)[(size_t)(row + i) * (N >> 1) + j] = f2bf(wv);
                }
            } else {
#pragma unroll
                for (int i = 0; i < 4; i++) {
                    if (EPI == 1)
                        ((short*)Cv)[(size_t)(row + i) * N + col] = f2bf(acc[m][n][i]);
                    else
                        ((float*)Cv)[(size_t)(row + i) * N + col] = acc[m][n][i];
                }
            }
        }
}

// ---------- RoPE + cosine_norm for q,k. qkvb bf16 [4096][3072] -> qn,kn bf16 [B][H][S][64] ----------
__global__ void k_rope(const short* __restrict__ qkvb, const float* __restrict__ cost,
                       const float* __restrict__ sint, const float* __restrict__ sqk,
                       short* __restrict__ qn, short* __restrict__ kn) {
    int wid = blockIdx.x * 4 + (threadIdx.x >> 6);   // [0, 65536)
    int lane = threadIdx.x & 63;
    int h = wid & 15;
    int s = (wid >> 4) & 2047;
    int b = wid >> 15;
    int row = b * 2048 + s;
    int j = lane & 31;
    float cs = cost[s * 32 + j];
    float sn = sint[s * 32 + j];
    float eff = sqk[h * 64 + lane] * 32.0f;          // s_qk * sqrt(DIM)
    size_t inbase = (size_t)row * 3072 + h * 64 + lane;
    size_t outbase = ((size_t)(b * 16 + h) * 2048 + s) * 64 + lane;
    {   // q  (extra *8 = sqrt(HD) logit scale folded in)
        float v = bf2f(qkvb[inbase]);
        float vp = __shfl_xor(v, 32, 64);
        float vr = (lane < 32) ? v * cs - vp * sn : v * cs + vp * sn;
        float ss = vr * vr;
#pragma unroll
        for (int o = 1; o < 64; o <<= 1) ss += __shfl_xor(ss, o, 64);
        float sc = eff * 8.0f / fmaxf(sqrtf(ss), 1e-6f);
        qn[outbase] = f2bf(vr * sc);
    }
    {   // k
        float v = bf2f(qkvb[inbase + 1024]);
        float vp = __shfl_xor(v, 32, 64);
        float vr = (lane < 32) ? v * cs - vp * sn : v * cs + vp * sn;
        float ss = vr * vr;
#pragma unroll
        for (int o = 1; o < 64; o <<= 1) ss += __shfl_xor(ss, o, 64);
        float sc = eff / fmaxf(sqrtf(ss), 1e-6f);
        kn[outbase] = f2bf(vr * sc);
    }
}

// ---------- V transpose: qkvb v-part bf16 -> vt bf16 [B][H][64][2048] ----------
__global__ void k_vtrans(const short* __restrict__ qkvb, short* __restrict__ vt) {
    __shared__ short tile[64][72];
    int blk = blockIdx.x;
    int st = blk & 31, h = (blk >> 5) & 15, b = blk >> 9;
    int s0 = st * 64;
    int t = threadIdx.x;
    int sl = t >> 2, c0 = (t & 3) * 16;
    const short* src = qkvb + (size_t)(b * 2048 + s0 + sl) * 3072 + 2048 + h * 64 + c0;
    bf16x8 a0 = *(const bf16x8*)src;
    bf16x8 a1 = *(const bf16x8*)(src + 8);
#pragma unroll
    for (int jj = 0; jj < 8; jj++) { tile[sl][c0 + jj] = a0[jj]; tile[sl][c0 + 8 + jj] = a1[jj]; }
    __syncthreads();
    int hd = t >> 2, sc = (t & 3) * 16;
    bf16x8 p0, p1;
#pragma unroll
    for (int jj = 0; jj < 8; jj++) { p0[jj] = tile[sc + jj][hd]; p1[jj] = tile[sc + 8 + jj][hd]; }
    size_t obase = ((size_t)((b * 16 + h) * 64 + hd)) * 2048 + s0 + sc;
    *(bf16x8*)&vt[obase] = p0;
    *(bf16x8*)&vt[obase + 8] = p1;
}

// ---------- flash attention (causal), static-max softmax, split-K x2, XCD-binned ----------
// 512 threads = 8 waves; block covers 256 q-rows (wave w: rows qb*256 + w*32 .. +32).
// 1D grid 512: bid -> xcd = bid&7; each XCD gets 4 full (b,h) groups (K/V fits its L2).
// Within group, (qb,hf) heaviest-first. Tiles [hf*(2qb+2), (hf+1)*(2qb+2)) of 64 keys.
// Unnormalized partial O (bf16) + row-sum lsum (f32); k_comb normalizes.
__launch_bounds__(512)
__global__ void k_attn(const short* __restrict__ qn, const short* __restrict__ kn,
                       const short* __restrict__ vt, short* __restrict__ opart,
                       float* __restrict__ lsump) {
    __shared__ __align__(16) short Ks[2][64 * 64];   // 2 x 8 KB
    __shared__ __align__(16) short Vs[2][64 * 64];   // 2 x 8 KB
    __shared__ __align__(16) short Ps[8][32 * 64];   // 8 x 4 KB
    const int t = threadIdx.x;
    const int w = t >> 6, lane = t & 63;
    const int bid = blockIdx.x;
    const int xcd = bid & 7, kk_ = bid >> 3;
    const int bhg = xcd + ((kk_ >> 4) << 3);         // 0..31
    const int xi = kk_ & 15;
    const int qb = 7 - (xi >> 1), hf = xi & 1;
    const int h = bhg & 15, b = bhg >> 4;
    const int bh = b * 16 + h;
    const int qw = qb * 256 + w * 32;
    const int lr = lane & 15, lg = lane >> 4;
    const short* Qb = qn + (size_t)bh * 2048 * 64;
    const short* Kb = kn + (size_t)bh * 2048 * 64;
    const short* Vb = vt + (size_t)bh * 64 * 2048;
    char* pwc = (char*)&Ps[w][0];

    bf16x8 qf[2][2];
#pragma unroll
    for (int mi = 0; mi < 2; mi++)
#pragma unroll
        for (int kk = 0; kk < 2; kk++)
            qf[mi][kk] = *(const bf16x8*)&Qb[(size_t)(qw + mi * 16 + lr) * 64 + kk * 32 + lg * 8];

    f32x4 oacc[2][4];
#pragma unroll
    for (int mi = 0; mi < 2; mi++)
#pragma unroll
        for (int ct = 0; ct < 4; ct++) oacc[mi][ct] = (f32x4){0.f, 0.f, 0.f, 0.f};
    float psum[2][4];
#pragma unroll
    for (int mi = 0; mi < 2; mi++)
#pragma unroll
        for (int i = 0; i < 4; i++) psum[mi][i] = 0.0f;

    const int ktn = 2 * qb + 2;
    const int kt0 = hf * ktn, kt1 = kt0 + ktn;

#define STAGE_KV(bi, kbase)                                                          \
    {                                                                                \
        int row = w * 8 + (lane >> 3);                                               \
        int scol = (lane & 7) ^ (row & 7);                                           \
        gload16(Kb + (size_t)((kbase) + row) * 64 + scol * 8,                        \
                &Ks[bi][(w * 8) * 64]);                                              \
        gload16(Vb + (size_t)row * 2048 + (kbase) + scol * 8,                        \
                &Vs[bi][(w * 8) * 64]);                                              \
    }

    STAGE_KV(0, kt0 << 6);

    for (int kt = kt0; kt < kt1; kt++) {
        const int kbase = kt << 6;
        const int cur = (kt - kt0) & 1;
        __syncthreads();                      // drains vmcnt -> buf cur resident
        if (kt + 1 < kt1) STAGE_KV(cur ^ 1, (kt + 1) << 6);

        // ---- QK^T ----
        bf16x8 kf[4][2];
#pragma unroll
        for (int ni = 0; ni < 4; ni++)
#pragma unroll
            for (int kk = 0; kk < 2; kk++) {
                int row = ni * 16 + lr;
                kf[ni][kk] = *(const bf16x8*)&Ks[cur][row * 64 + (((kk * 4 + lg) ^ (row & 7)) << 3)];
            }
        f32x4 sv[2][4];
#pragma unroll
        for (int mi = 0; mi < 2; mi++)
#pragma unroll
            for (int ni = 0; ni < 4; ni++) {
                f32x4 s = (f32x4){0.f, 0.f, 0.f, 0.f};
                s = mfma16(qf[mi][0], kf[ni][0], s);
                s = mfma16(qf[mi][1], kf[ni][1], s);
                sv[mi][ni] = s;
            }
        // ---- causal mask (wave-uniform branch) ----
        if (kbase + 63 > qw) {
#pragma unroll
            for (int mi = 0; mi < 2; mi++)
#pragma unroll
                for (int ni = 0; ni < 4; ni++)
#pragma unroll
                    for (int i = 0; i < 4; i++) {
                        int qg = qw + mi * 16 + lg * 4 + i;
                        int kg = kbase + ni * 16 + lr;
                        if (kg > qg) sv[mi][ni][i] = -3.0e38f;
                    }
        }
        // ---- static-max softmax: logits bounded by 8; p = exp(s-9) ----
#pragma unroll
        for (int mi = 0; mi < 2; mi++) {
#pragma unroll
            for (int ni = 0; ni < 4; ni++)
#pragma unroll
                for (int i = 0; i < 4; i++) {
                    float p = exp2f((sv[mi][ni][i] - 9.0f) * 1.44269504f);
                    sv[mi][ni][i] = p;
                    psum[mi][i] += p;
                }
#pragma unroll
            for (int ni = 0; ni < 4; ni++)
#pragma unroll
                for (int i = 0; i < 4; i++) {
                    int row = mi * 16 + lg * 4 + i;
                    int col = ni * 16 + lr;
                    unsigned off = (unsigned)(row * 128 + col * 2) ^ ((unsigned)(row & 7) << 4);
                    *(short*)(pwc + off) = f2bf(sv[mi][ni][i]);
                }
        }
        // ---- PV: O += P x V^T (unnormalized, no rescale) ----
        bf16x8 pa[2][2];
#pragma unroll
        for (int mi = 0; mi < 2; mi++)
#pragma unroll
            for (int kk = 0; kk < 2; kk++) {
                int row = mi * 16 + lr;
                unsigned off = (unsigned)(row * 128 + kk * 64 + lg * 16) ^ ((unsigned)(row & 7) << 4);
                pa[mi][kk] = *(const bf16x8*)(pwc + off);
            }
        bf16x8 vf[4][2];
#pragma unroll
        for (int ct = 0; ct < 4; ct++)
#pragma unroll
            for (int kk = 0; kk < 2; kk++) {
                int row = ct * 16 + lr;
                vf[ct][kk] = *(const bf16x8*)&Vs[cur][row * 64 + (((kk * 4 + lg) ^ (row & 7)) << 3)];
            }
#pragma unroll
        for (int mi = 0; mi < 2; mi++)
#pragma unroll
            for (int ct = 0; ct < 4; ct++) {
                oacc[mi][ct] = mfma16(pa[mi][0], vf[ct][0], oacc[mi][ct]);
                oacc[mi][ct] = mfma16(pa[mi][1], vf[ct][1], oacc[mi][ct]);
            }
    }
#undef STAGE_KV

    // ---- one-time lsum reduce across the 16 lr lanes ----
#pragma unroll
    for (int o = 1; o < 16; o <<= 1)
#pragma unroll
        for (int mi = 0; mi < 2; mi++)
#pragma unroll
            for (int i = 0; i < 4; i++)
                psum[mi][i] += __shfl_xor(psum[mi][i], o, 64);

    short* aob = opart + (size_t)hf * 4096 * 1024 + ((size_t)(b * 2048 + qw) * 1024) + h * 64;
#pragma unroll
    for (int mi = 0; mi < 2; mi++)
#pragma unroll
        for (int ct = 0; ct < 4; ct++)
#pragma unroll
            for (int i = 0; i < 4; i++) {
                int q = mi * 16 + lg * 4 + i;
                aob[(size_t)q * 1024 + ct * 16 + lr] = f2bf(oacc[mi][ct][i]);
            }
    if (lr == 0) {
#pragma unroll
        for (int mi = 0; mi < 2; mi++)
#pragma unroll
            for (int i = 0; i < 4; i++)
                lsump[hf * 65536 + bh * 2048 + qw + mi * 16 + lg * 4 + i] = psum[mi][i];
    }
}

// ---------- combine split-K partials: ao = (O0+O1)/(l0+l1), bf16 ----------
__global__ void k_comb(const short* __restrict__ op, const float* __restrict__ ls,
                       short* __restrict__ ao) {
    int i = (blockIdx.x * 256 + threadIdx.x) * 4;     // over 4096*1024
    int row = i >> 10, col = i & 1023;
    int idx = ((row >> 11) * 16 + (col >> 6)) * 2048 + (row & 2047);
    float rl = 1.0f / (ls[idx] + ls[65536 + idx]);
    short4 a = *(const short4*)(op + i);
    short4 c = *(const short4*)(op + 4194304 + i);
    short4 o;
    o.x = f2bf((bf2f(a.x) + bf2f(c.x)) * rl);
    o.y = f2bf((bf2f(a.y) + bf2f(c.y)) * rl);
    o.z = f2bf((bf2f(a.z) + bf2f(c.z)) * rl);
    o.w = f2bf((bf2f(a.w) + bf2f(c.w)) * rl);
    *(short4*)(ao + i) = o;
}

// ---------- residual + double cosine_norm (base/outf may alias: no restrict on them) ----------
__global__ void k_resnorm(const float* base, const float* __restrict__ pre,
                          const float* __restrict__ alpha, float* outf,
                          short* __restrict__ outb) {
    __shared__ float red1[4], red2[4];
    int row = blockIdx.x;
    int t = threadIdx.x;
    int w = t >> 6;
    const float4 p = *(const float4*)(pre + (size_t)row * 1024 + t * 4);
    float ss = p.x * p.x + p.y * p.y + p.z * p.z + p.w * p.w;
#pragma unroll
    for (int o = 1; o < 64; o <<= 1) ss += __shfl_xor(ss, o, 64);
    if ((t & 63) == 0) red1[w] = ss;
    __syncthreads();
    float inv1 = 1.0f / fmaxf(sqrtf(red1[0] + red1[1] + red1[2] + red1[3]), 1e-6f);
    const float4 bx = *(const float4*)(base + (size_t)row * 1024 + t * 4);
    const float4 av = *(const float4*)(alpha + t * 4);
    float4 tm;
    tm.x = bx.x + av.x * (p.x * inv1 - bx.x);
    tm.y = bx.y + av.y * (p.y * inv1 - bx.y);
    tm.z = bx.z + av.z * (p.z * inv1 - bx.z);
    tm.w = bx.w + av.w * (p.w * inv1 - bx.w);
    float ss2 = tm.x * tm.x + tm.y * tm.y + tm.z * tm.z + tm.w * tm.w;
#pragma unroll
    for (int o = 1; o < 64; o <<= 1) ss2 += __shfl_xor(ss2, o, 64);
    if ((t & 63) == 0) red2[w] = ss2;
    __syncthreads();
    float inv2 = 1.0f / fmaxf(sqrtf(red2[0] + red2[1] + red2[2] + red2[3]), 1e-6f);
    float4 hv;
    hv.x = tm.x * inv2; hv.y = tm.y * inv2; hv.z = tm.z * inv2; hv.w = tm.w * inv2;
    if (outf) *(float4*)(outf + (size_t)row * 1024 + t * 4) = hv;
    if (outb) {
        short4 o4;
        o4.x = f2bf(hv.x); o4.y = f2bf(hv.y); o4.z = f2bf(hv.z); o4.w = f2bf(hv.w);
        *(short4*)(outb + (size_t)row * 1024 + t * 4) = o4;
    }
}

// ---------- launch ----------
// Workspace (lifetime-overlaid, peak 76,152,832 B = known-safe):
//  [0, 25821184)   weights bf16^T (wqkvT, woT, wugT interleaved, wdownT) + rope tables
//  B 25821184      xbf(#1-#4) -> vt(#6-#7) -> h1bf(#10-#11)              8 MB
//  C 34209792      qkvb(#4-#6) 24MB -> opart[2](#7-#8) 16MB -> hA(#9-#10) 16MB -> wmlp(#11-#12) 22.5MB
//  50987008        lsum (#7-#8) 0.5MB
//  52035584        ao (#8-#9) 8MB
//  59375616        qn(#5-#7) -> hM(#12-#13) 16MB
//  67764224        kn(#5-#7)
extern "C" void kernel_launch(void* const* d_in, const int* in_sizes, int n_in,
                              void* d_out, int out_size, void* d_ws, size_t ws_size,
                              hipStream_t stream) {
    (void)in_sizes; (void)n_in; (void)out_size; (void)ws_size;
    const float* x   = (const float*)d_in[0];
    const float* Wq  = (const float*)d_in[1];
    const float* Wk  = (const float*)d_in[2];
    const float* Wv  = (const float*)d_in[3];
    const float* Wo  = (const float*)d_in[4];
    const float* sqk = (const float*)d_in[5];
    const float* aA  = (const float*)d_in[6];
    const float* Wup = (const float*)d_in[7];
    const float* Wg  = (const float*)d_in[8];
    const float* Wd  = (const float*)d_in[9];
    const float* su  = (const float*)d_in[10];
    const float* sv  = (const float*)d_in[11];
    const float* aM  = (const float*)d_in[12];

    char* ws = (char*)d_ws;
    short* wqkvT  = (short*)(ws + 0);          // [3072][1024]
    short* woT    = (short*)(ws + 6291456);    // [1024][1024]
    short* wugT   = (short*)(ws + 8388608);    // [5504][1024] interleaved up/gate
    short* wdownT = (short*)(ws + 19660800);   // [1024][2752]
    float* cost   = (float*)(ws + 25296896);
    float* sint   = (float*)(ws + 25559040);
    short* xbf    = (short*)(ws + 25821184);
    short* qkvb   = (short*)(ws + 34209792);   // [4096][3072] bf16
    short* qn     = (short*)(ws + 59375616);
    short* kn     = (short*)(ws + 67764224);
    short* vt     = (short*)(ws + 25821184);   // reuse xbf
    short* opart  = (short*)(ws + 34209792);   // reuse qkvb: [2][4096][1024] bf16
    float* lsum   = (float*)(ws + 50987008);   // [2][32][2048] f32
    short* ao     = (short*)(ws + 52035584);   // [4096][1024] bf16
    float* hA     = (float*)(ws + 34209792);   // reuse opart after comb
    float* h1f    = (float*)d_out;             // d_out doubles as h1 storage
    short* h1bf   = (short*)(ws + 25821184);   // reuse vt
    short* wmlp   = (short*)(ws + 34209792);   // reuse hA: [4096][2752]
    float* hM     = (float*)(ws + 59375616);   // reuse qn/kn

    k_cvt_bf16<<<4096, 256, 0, stream>>>(x, xbf, 4194304);
    k_transpose_cvt<<<dim3(32, 32), 256, 0, stream>>>(Wq, wqkvT,           1024, 1024, 1024, 1024, 1, 0);
    k_transpose_cvt<<<dim3(32, 32), 256, 0, stream>>>(Wk, wqkvT + 1048576, 1024, 1024, 1024, 1024, 1, 0);
    k_transpose_cvt<<<dim3(32, 32), 256, 0, stream>>>(Wv, wqkvT + 2097152, 1024, 1024, 1024, 1024, 1, 0);
    k_transpose_cvt<<<dim3(32, 32), 256, 0, stream>>>(Wo, woT,             1024, 1024, 1024, 1024, 1, 0);
    k_transpose_cvt<<<dim3(86, 32), 256, 0, stream>>>(Wup, wugT, 1024, 2730, 1024, 2752, 2, 0);
    k_transpose_cvt<<<dim3(86, 32), 256, 0, stream>>>(Wg,  wugT, 1024, 2730, 1024, 2752, 2, 1);
    k_transpose_cvt<<<dim3(32, 86), 256, 0, stream>>>(Wd,  wdownT, 2730, 1024, 2752, 1024, 1, 0);
    k_freqs<<<256, 256, 0, stream>>>(cost, sint);

    k_gemm128<1><<<dim3(32, 24), 256, 0, stream>>>(xbf, wqkvT, qkvb, 4096, 3072, 1024, nullptr, nullptr);
    k_rope<<<16384, 256, 0, stream>>>(qkvb, cost, sint, sqk, qn, kn);
    k_vtrans<<<1024, 256, 0, stream>>>(qkvb, vt);
    k_attn<<<512, 512, 0, stream>>>(qn, kn, vt, opart, lsum);
    k_comb<<<4096, 256, 0, stream>>>(opart, lsum, ao);
    k_gemm128<0><<<dim3(32, 8), 256, 0, stream>>>(ao, woT, hA, 4096, 1024, 1024, nullptr, nullptr);
    k_resnorm<<<4096, 256, 0, stream>>>(x, hA, aA, h1f, h1bf);
    k_gemm128<2><<<dim3(32, 43), 256, 0, stream>>>(h1bf, wugT, wmlp, 4096, 5504, 1024, su, sv);
    k_gemm128<0><<<dim3(32, 8), 256, 0, stream>>>(wmlp, wdownT, hM, 4096, 1024, 2752, nullptr, nullptr);
    k_resnorm<<<4096, 256, 0, stream>>>(h1f, hM, aM, (float*)d_out, (short*)nullptr);
}